// Round 3
// baseline (1669.958 us; speedup 1.0000x reference)
//
#include <hip/hip_runtime.h>
#include <math.h>

#define NPTS 50000
#define MN 1024
#define KK 64
#define DPT 64
#define DN 256
#define BCORR 256
#define OUTC 1024
#define OTI 100
#define NEGV (-1e4f)
#define EPSV 1e-8f
#define CAPL 512
#define CCAP 16384
#define HBLK 256   // blocks for histogram passes

// ---------------- utility ----------------
__global__ void zero_u32_kernel(unsigned* __restrict__ p, int n){
  for (int i=blockIdx.x*blockDim.x+threadIdx.x; i<n; i+=gridDim.x*blockDim.x) p[i]=0u;
}
__global__ void zero_f32_kernel(float* __restrict__ p, int n){
  for (int i=blockIdx.x*blockDim.x+threadIdx.x; i<n; i+=gridDim.x*blockDim.x) p[i]=0.0f;
}

__device__ __forceinline__ float blockReduceSum256(float v, float* red){
  int t=threadIdx.x;
  red[t]=v; __syncthreads();
  #pragma unroll
  for (int s=128;s>0;s>>=1){ if(t<s) red[t]+=red[t+s]; __syncthreads(); }
  float r=red[0]; __syncthreads();
  return r;
}

__device__ __forceinline__ float wave_max64(float x){
  #pragma unroll
  for (int m=1;m<64;m<<=1) x=fmaxf(x,__shfl_xor(x,m,64));
  return x;
}
__device__ __forceinline__ float wave_sum64(float x){
  #pragma unroll
  for (int m=1;m<64;m<<=1) x+=__shfl_xor(x,m,64);
  return x;
}

// node feats: out = l2norm(x @ W^T + b); sq = sum(out^2) (for sq_dist fidelity)
__global__ __launch_bounds__(256) void node_feat_kernel(
    const float* __restrict__ x, const float* __restrict__ W,
    const float* __restrict__ bias, float* __restrict__ out, float* __restrict__ sq){
  __shared__ float xs[DN];
  __shared__ float red[256];
  int m=blockIdx.x, i=threadIdx.x;
  xs[i]=x[m*DN+i];
  __syncthreads();
  float acc=bias[i];
  const float* wr=W+(size_t)i*DN;
  for (int k=0;k<DN;k++) acc=fmaf(wr[k],xs[k],acc);
  float ssq=blockReduceSum256(acc*acc,red);
  float o=acc/sqrtf(ssq);
  out[m*DN+i]=o;
  float s2=blockReduceSum256(o*o,red);
  if(i==0) sq[m]=s2;
}

// nearest node per point (argmin over gram-trick distance, first-min tie rule)
__global__ __launch_bounds__(256) void p2n_kernel(
    const float* __restrict__ pts, const float* __restrict__ nodes, int* __restrict__ p2n){
  __shared__ float nx[MN], ny[MN], nz[MN], nn[MN];
  for (int j=threadIdx.x;j<MN;j+=256){
    float a=nodes[j*3+0], b=nodes[j*3+1], c=nodes[j*3+2];
    nx[j]=a; ny[j]=b; nz[j]=c; nn[j]=a*a+b*b+c*c;
  }
  __syncthreads();
  int id=blockIdx.x*256+threadIdx.x;
  if (id>=NPTS) return;
  float px=pts[id*3+0], py=pts[id*3+1], pz=pts[id*3+2];
  float pp=px*px+py*py+pz*pz;
  float best=3.4e38f; int bi=0;
  for (int j=0;j<MN;j++){
    float d=pp+nn[j]-2.0f*(px*nx[j]+py*ny[j]+pz*nz[j]);
    if (d<best){best=d;bi=j;}
  }
  p2n[id]=bi;
}

__global__ __launch_bounds__(256) void scatter_kernel(
    const int* __restrict__ p2n, int* __restrict__ cnt, int* __restrict__ list){
  int id=blockIdx.x*256+threadIdx.x;
  if (id>=NPTS) return;
  int n=p2n[id];
  int t=atomicAdd(&cnt[n],1);
  if (t<CAPL) list[(size_t)n*CAPL+t]=id;
}

// per-node kNN: sort assigned points by (dist asc, idx asc), keep first 64, pad NPTS
__global__ __launch_bounds__(256) void knn_kernel(
    const float* __restrict__ pts, const float* __restrict__ nodes,
    const int* __restrict__ cnt, const int* __restrict__ list, int* __restrict__ knn){
  __shared__ float ds[CAPL];
  __shared__ int is[CAPL];
  int m=blockIdx.x;
  int c=cnt[m]; if (c>CAPL) c=CAPL;
  float ax=nodes[m*3+0], ay=nodes[m*3+1], az=nodes[m*3+2];
  float nn2=ax*ax+ay*ay+az*az;
  for (int e=threadIdx.x;e<c;e+=256){
    int p=list[(size_t)m*CAPL+e];
    float px=pts[p*3+0],py=pts[p*3+1],pz=pts[p*3+2];
    float pp=px*px+py*py+pz*pz;
    ds[e]=pp+nn2-2.0f*(px*ax+py*ay+pz*az);
    is[e]=p;
  }
  for (int k=threadIdx.x;k<KK;k+=256) knn[m*KK+k]=NPTS;
  __syncthreads();
  for (int e=threadIdx.x;e<c;e+=256){
    float d=ds[e]; int p=is[e]; int r=0;
    for (int j=0;j<c;j++){
      float dj=ds[j];
      r += (dj<d || (dj==d && is[j]<p)) ? 1 : 0;
    }
    if (r<KK) knn[m*KK+r]=p;
  }
}

// coarse scores: exp(-(tt+ss-2*dot)) masked by node validity
__global__ __launch_bounds__(256) void coarse_score_kernel(
    const float* __restrict__ tf, const float* __restrict__ sf,
    const float* __restrict__ tt, const float* __restrict__ ssv,
    const int* __restrict__ cnt_t, const int* __restrict__ cnt_s, float* __restrict__ S){
  __shared__ float ti[DN];
  int i=blockIdx.x;
  for (int k=threadIdx.x;k<DN;k+=256) ti[k]=tf[(size_t)i*DN+k];
  __syncthreads();
  int tv=cnt_t[i]>0;
  float tti=tt[i];
  for (int j=threadIdx.x;j<MN;j+=256){
    const float* sr=sf+(size_t)j*DN;
    float dot=0.0f;
    for (int k=0;k<DN;k++) dot=fmaf(ti[k],sr[k],dot);
    float d=tti+ssv[j]-2.0f*dot;
    float v=expf(-d);
    S[(size_t)i*MN+j]=(tv && cnt_s[j]>0)? v : 0.0f;
  }
}

__global__ __launch_bounds__(256) void rowsum_kernel(const float* __restrict__ S, float* __restrict__ rs){
  __shared__ float red[256];
  int i=blockIdx.x;
  float a=0;
  for (int j=threadIdx.x;j<MN;j+=256) a+=S[(size_t)i*MN+j];
  float r=blockReduceSum256(a,red);
  if (threadIdx.x==0) rs[i]=r;
}
__global__ __launch_bounds__(256) void colsum_kernel(const float* __restrict__ S, float* __restrict__ cs){
  __shared__ float red[256];
  int j=blockIdx.x;
  float a=0;
  for (int i=threadIdx.x;i<MN;i+=256) a+=S[(size_t)i*MN+j];
  float r=blockReduceSum256(a,red);
  if (threadIdx.x==0) cs[j]=r;
}
__global__ __launch_bounds__(256) void dualnorm_kernel(
    float* __restrict__ S, const float* __restrict__ rs, const float* __restrict__ cs){
  int idx=blockIdx.x*256+threadIdx.x;
  int i=idx>>10, j=idx&1023;
  float v=S[idx];
  S[idx]=(v/(rs[i]+EPSV))*(v/(cs[j]+EPSV));
}

// ---------- deterministic top-k, contention-free two-level histogram ----------
// meta layout: [0]=T (16-bit bucket threshold), [1]=candidate counter,
//              [2]=coarse bin CB, [3]=count above CB
__global__ __launch_bounds__(256) void hist_coarse_kernel(
    const float* __restrict__ arr, int n, unsigned* __restrict__ partial){
  __shared__ unsigned lh[256];
  lh[threadIdx.x]=0u; __syncthreads();
  for (int i=blockIdx.x*256+threadIdx.x; i<n; i+=gridDim.x*256){
    float v=arr[i];
    if (v>0.0f) atomicAdd(&lh[__float_as_uint(v)>>24],1u);
  }
  __syncthreads();
  partial[blockIdx.x*256+threadIdx.x]=lh[threadIdx.x];
}
__global__ __launch_bounds__(256) void scan_coarse_kernel(
    const unsigned* __restrict__ partial, int nblk, int k, unsigned* __restrict__ meta){
  __shared__ unsigned h[256];
  int t=threadIdx.x;
  unsigned a=0;
  for (int i=0;i<nblk;i++) a+=partial[(size_t)i*256+t];
  h[t]=a; __syncthreads();
  if (t==0){
    unsigned cum=0; int cb=-1; unsigned above=0;
    for (int b=255;b>=0;b--){
      if (cum+h[b] >= (unsigned)k){ cb=b; above=cum; break; }
      cum+=h[b];
    }
    if (cb<0){ cb=0; above=cum-h[0]; }   // fewer than k positives: T will be 0
    meta[2]=(unsigned)cb; meta[3]=above;
  }
}
__global__ __launch_bounds__(256) void hist_fine_kernel(
    const float* __restrict__ arr, int n, const unsigned* __restrict__ meta,
    unsigned* __restrict__ partial){
  __shared__ unsigned lh[256];
  lh[threadIdx.x]=0u; __syncthreads();
  unsigned CB=meta[2];
  for (int i=blockIdx.x*256+threadIdx.x; i<n; i+=gridDim.x*256){
    float v=arr[i];
    unsigned b=__float_as_uint(v);
    if (v>0.0f && (b>>24)==CB) atomicAdd(&lh[(b>>16)&255u],1u);
  }
  __syncthreads();
  partial[blockIdx.x*256+threadIdx.x]=lh[threadIdx.x];
}
__global__ __launch_bounds__(256) void scan_fine_kernel(
    const unsigned* __restrict__ partial, int nblk, int k, unsigned* __restrict__ meta){
  __shared__ unsigned h[256];
  int t=threadIdx.x;
  unsigned a=0;
  for (int i=0;i<nblk;i++) a+=partial[(size_t)i*256+t];
  h[t]=a; __syncthreads();
  if (t==0){
    unsigned CB=meta[2];
    unsigned cum=meta[3]; int sb=0;
    for (int b=255;b>=0;b--){
      if (cum+h[b] >= (unsigned)k){ sb=b; break; }
      cum+=h[b];
    }
    meta[0]=CB*256u+(unsigned)sb;
    meta[1]=0u;   // reset candidate counter for compact
  }
}
__global__ void compact_kernel(const float* __restrict__ arr, int n,
                               const unsigned* __restrict__ meta,
                               float* __restrict__ cv, int* __restrict__ ci,
                               unsigned* __restrict__ cnt){
  unsigned T=meta[0];
  for (int i=blockIdx.x*blockDim.x+threadIdx.x; i<n; i+=gridDim.x*blockDim.x){
    float v=arr[i];
    if (v>0.0f && (__float_as_uint(v)>>16)>=T){
      unsigned p=atomicAdd(cnt,1u);
      if (p<CCAP){ cv[p]=v; ci[p]=i; }
    }
  }
}
__global__ __launch_bounds__(256) void rank_coarse_kernel(
    const float* __restrict__ cv, const int* __restrict__ ci, const unsigned* __restrict__ meta,
    int* __restrict__ ti, int* __restrict__ si){
  int c=(int)meta[1]; if (c>CCAP) c=CCAP;
  int t=blockIdx.x*256+threadIdx.x;
  if (t>=c) return;
  float v=cv[t]; int idx=ci[t];
  int rk=0;
  for (int j=0;j<c;j++){
    float vj=cv[j]; int ij=ci[j];
    rk += (vj>v || (vj==v && ij<idx)) ? 1 : 0;
  }
  if (rk<BCORR){ ti[rk]=idx/MN; si[rk]=idx%MN; }
}
__global__ __launch_bounds__(256) void rank_fine_kernel(
    const float* __restrict__ cv, const int* __restrict__ ci, const unsigned* __restrict__ meta,
    const int* __restrict__ sel_t, const int* __restrict__ sel_s,
    const float* __restrict__ tpts, const float* __restrict__ spts,
    float* __restrict__ tp, float* __restrict__ sp, float* __restrict__ cs){
  int c=(int)meta[1]; if (c>CCAP) c=CCAP;
  int t=blockIdx.x*256+threadIdx.x;
  if (t>=c) return;
  float v=cv[t]; int idx=ci[t];
  int rk=0;
  for (int j=0;j<c;j++){
    float vj=cv[j]; int ij=ci[j];
    rk += (vj>v || (vj==v && ij<idx)) ? 1 : 0;
  }
  if (rk<OUTC){
    int b=idx>>12, r=(idx>>6)&63, cc=idx&63;
    int tpi=sel_t[b*KK+r], spi=sel_s[b*KK+cc];
    float tx=0,ty=0,tz=0,sx=0,sy=0,sz=0;
    if (tpi<NPTS){ tx=tpts[tpi*3]; ty=tpts[tpi*3+1]; tz=tpts[tpi*3+2]; }
    if (spi<NPTS){ sx=spts[spi*3]; sy=spts[spi*3+1]; sz=spts[spi*3+2]; }
    tp[rk*3+0]=tx; tp[rk*3+1]=ty; tp[rk*3+2]=tz;
    sp[rk*3+0]=sx; sp[rk*3+1]=sy; sp[rk*3+2]=sz;
    cs[rk]=v;
  }
}

// ---------- patch assembly / OT / fine ----------
__global__ void gather_sel_kernel(const int* __restrict__ ci, const int* __restrict__ knn,
                                  int* __restrict__ sel){
  int b=blockIdx.x, k=threadIdx.x;
  sel[b*KK+k]=knn[ci[b]*KK+k];
}

// selected point features: W(256x64) @ x + b; padded index -> zero vector
__global__ __launch_bounds__(256) void sel_feat_kernel(
    const int* __restrict__ sel, const float* __restrict__ ptf,
    const float* __restrict__ W, const float* __restrict__ bias, float* __restrict__ out){
  __shared__ float xs[DPT];
  int j=blockIdx.x, i=threadIdx.x;
  int p=sel[j];
  if (p==NPTS){ out[(size_t)j*DN+i]=0.0f; return; }   // block-uniform branch
  if (i<DPT) xs[i]=ptf[(size_t)p*DPT+i];
  __syncthreads();
  float acc=bias[i];
  const float* wr=W+(size_t)i*DPT;
  for (int k=0;k<DPT;k++) acc=fmaf(wr[k],xs[k],acc);
  out[(size_t)j*DN+i]=acc;
}

// build padded OT input P (65x65) per batch, with alpha dustbin + NEG masking
__global__ __launch_bounds__(256) void pbuild_kernel(
    const float* __restrict__ ft, const float* __restrict__ fs,
    const int* __restrict__ sel_t, const int* __restrict__ sel_s,
    const float* __restrict__ alpha_p, float* __restrict__ P){
  __shared__ int tm[KK], smk[KK];
  int b=blockIdx.x;
  if (threadIdx.x<KK){
    tm[threadIdx.x]= (sel_t[b*KK+threadIdx.x]!=NPTS);
    smk[threadIdx.x]= (sel_s[b*KK+threadIdx.x]!=NPTS);
  }
  __syncthreads();
  float alpha=alpha_p[0];
  const float* tb=ft+(size_t)b*KK*DN;
  const float* sb=fs+(size_t)b*KK*DN;
  float* Pb=P+(size_t)b*65*65;
  for (int e=threadIdx.x;e<65*65;e+=256){
    int r=e/65, c=e-65*r;
    bool inv=(r<KK && !tm[r]) || (c<KK && !smk[c]);
    float val;
    if (r==KK || c==KK) val=alpha;
    else {
      const float* tr=tb+(size_t)r*DN;
      const float* sr=sb+(size_t)c*DN;
      float dot=0.0f;
      for (int k=0;k<DN;k++) dot=fmaf(tr[k],sr[k],dot);
      val=dot*0.0625f;   // / sqrt(256)
    }
    Pb[e]= inv ? NEGV : val;
  }
}

// Sinkhorn: 100 iters, one block per batch, wave-parallel logsumexp
// 1024 threads = 16 waves; wave w handles rows {w, w+16, w+32, w+48} (+row 64 on w0)
__global__ __launch_bounds__(1024) void ot_kernel(
    float* __restrict__ P, const int* __restrict__ sel_t, const int* __restrict__ sel_s){
  __shared__ float Ps[65*65];
  __shared__ float u[65], v[65], lmu[65], lnu[65];
  __shared__ float nrm_s;
  __shared__ int nrs, ncs;
  int b=blockIdx.x, t=threadIdx.x;
  int wid=t>>6, lane=t&63;
  float* Pg=P+(size_t)b*65*65;
  for (int e=t;e<65*65;e+=1024) Ps[e]=Pg[e];
  if (t==0){
    int nr=0,nc=0;
    for (int k=0;k<KK;k++){ nr+=(sel_t[b*KK+k]!=NPTS); nc+=(sel_s[b*KK+k]!=NPTS); }
    nrs=nr; ncs=nc;
    nrm_s=-logf((float)(nr+nc));
  }
  __syncthreads();
  if (t<65){
    bool rv=(t<KK)? (sel_t[b*KK+t]!=NPTS) : true;
    bool cvv=(t<KK)? (sel_s[b*KK+t]!=NPTS) : true;
    float lm=(t==KK)? (logf((float)ncs)+nrm_s) : nrm_s;
    float ln=(t==KK)? (logf((float)nrs)+nrm_s) : nrm_s;
    lmu[t]= rv? lm : NEGV;
    lnu[t]= cvv? ln : NEGV;
    u[t]=0.0f; v[t]=0.0f;
  }
  __syncthreads();
  for (int it=0; it<OTI; it++){
    // ---- u-pass: one wave per row, lanes over columns ----
    #pragma unroll
    for (int q=0;q<4;q++){
      int r=wid+16*q;
      float a=Ps[r*65+lane]+v[lane];
      float a64=Ps[r*65+64]+v[64];              // same-addr broadcast
      float mx=wave_max64(fmaxf(a,a64));
      float e=expf(a-mx)+((lane==0)? expf(a64-mx) : 0.0f);
      float s=wave_sum64(e);
      if (lane==0) u[r]=lmu[r]-(logf(s)+mx);
    }
    if (wid==0){
      int r=64;
      float a=Ps[r*65+lane]+v[lane];
      float a64=Ps[r*65+64]+v[64];
      float mx=wave_max64(fmaxf(a,a64));
      float e=expf(a-mx)+((lane==0)? expf(a64-mx) : 0.0f);
      float s=wave_sum64(e);
      if (lane==0) u[r]=lmu[r]-(logf(s)+mx);
    }
    __syncthreads();
    // ---- v-pass: one wave per column, lanes over rows ----
    #pragma unroll
    for (int q=0;q<4;q++){
      int c=wid+16*q;
      float a=Ps[lane*65+c]+u[lane];
      float a64=Ps[64*65+c]+u[64];
      float mx=wave_max64(fmaxf(a,a64));
      float e=expf(a-mx)+((lane==0)? expf(a64-mx) : 0.0f);
      float s=wave_sum64(e);
      if (lane==0) v[c]=lnu[c]-(logf(s)+mx);
    }
    if (wid==0){
      int c=64;
      float a=Ps[lane*65+c]+u[lane];
      float a64=Ps[64*65+c]+u[64];
      float mx=wave_max64(fmaxf(a,a64));
      float e=expf(a-mx)+((lane==0)? expf(a64-mx) : 0.0f);
      float s=wave_sum64(e);
      if (lane==0) v[c]=lnu[c]-(logf(s)+mx);
    }
    __syncthreads();
  }
  for (int e=t;e<65*65;e+=1024){
    int r=e/65, c=e-65*r;
    Pg[e]=Ps[e]+u[r]+v[c]-nrm_s;
  }
}

// fine prep: s=exp(ms[:, :64, :64]); mutual top-3 + threshold + masks -> sm
__global__ __launch_bounds__(256) void fineprep_kernel(
    const float* __restrict__ P, const int* __restrict__ sel_t, const int* __restrict__ sel_s,
    float* __restrict__ smout){
  __shared__ float s[KK*KK];
  __shared__ unsigned long long rowm[KK], colm[KK];
  __shared__ int tmk[KK], smk[KK];
  int b=blockIdx.x, t=threadIdx.x;
  const float* Pb=P+(size_t)b*65*65;
  for (int e=t;e<KK*KK;e+=256){
    int r=e>>6, c=e&63;
    s[e]=expf(Pb[r*65+c]);
  }
  if (t<KK){ tmk[t]=(sel_t[b*KK+t]!=NPTS); smk[t]=(sel_s[b*KK+t]!=NPTS); }
  __syncthreads();
  if (t<KK){
    float v1=-1,v2=-1,v3=-1; int i1=0,i2=0,i3=0;
    const float* row=s+t*KK;
    for (int c=0;c<KK;c++){ float v=row[c];
      if (v>v1){v3=v2;i3=i2;v2=v1;i2=i1;v1=v;i1=c;}
      else if (v>v2){v3=v2;i3=i2;v2=v;i2=c;}
      else if (v>v3){v3=v;i3=c;}
    }
    rowm[t]=(1ULL<<i1)|(1ULL<<i2)|(1ULL<<i3);
  } else if (t<2*KK){
    int c=t-KK;
    float v1=-1,v2=-1,v3=-1; int i1=0,i2=0,i3=0;
    for (int r=0;r<KK;r++){ float v=s[r*KK+c];
      if (v>v1){v3=v2;i3=i2;v2=v1;i2=i1;v1=v;i1=r;}
      else if (v>v2){v3=v2;i3=i2;v2=v;i2=r;}
      else if (v>v3){v3=v;i3=r;}
    }
    colm[c]=(1ULL<<i1)|(1ULL<<i2)|(1ULL<<i3);
  }
  __syncthreads();
  for (int e=t;e<KK*KK;e+=256){
    int r=e>>6, c=e&63;
    float v=s[e];
    bool keep = ((rowm[r]>>c)&1ULL) && ((colm[c]>>r)&1ULL) && (v>0.05f) && tmk[r] && smk[c];
    smout[(size_t)b*KK*KK+e]= keep? v : 0.0f;
  }
}

extern "C" void kernel_launch(void* const* d_in, const int* in_sizes, int n_in,
                              void* d_out, int out_size, void* d_ws, size_t ws_size,
                              hipStream_t stream){
  const float* src_pts=(const float*)d_in[0];
  const float* tgt_pts=(const float*)d_in[1];
  const float* src_pf =(const float*)d_in[2];
  const float* tgt_pf =(const float*)d_in[3];
  const float* src_nf =(const float*)d_in[4];
  const float* tgt_nf =(const float*)d_in[5];
  const float* src_nx =(const float*)d_in[6];
  const float* tgt_nx =(const float*)d_in[7];
  const float* cw=(const float*)d_in[8];
  const float* cb=(const float*)d_in[9];
  const float* fw=(const float*)d_in[10];
  const float* fb=(const float*)d_in[11];
  const float* alpha=(const float*)d_in[12];

  char* ws=(char*)d_ws;
  size_t off=0;
  auto A=[&](size_t bytes)->char*{
    char* p=ws+off; off+=(bytes+255)&~(size_t)255; return p; };

  float* tf    =(float*)A((size_t)MN*DN*4);
  float* sfb   =(float*)A((size_t)MN*DN*4);
  float* tt    =(float*)A(MN*4);
  float* ssv   =(float*)A(MN*4);
  int*   p2n_s =(int*)A((size_t)NPTS*4);
  int*   p2n_t =(int*)A((size_t)NPTS*4);
  int*   cnt_s =(int*)A(MN*4);
  int*   cnt_t =(int*)A(MN*4);
  int*   list_s=(int*)A((size_t)MN*CAPL*4);
  int*   list_t=(int*)A((size_t)MN*CAPL*4);
  int*   knn_s =(int*)A((size_t)MN*KK*4);
  int*   knn_t =(int*)A((size_t)MN*KK*4);
  float* Smat  =(float*)A((size_t)MN*MN*4);
  unsigned* partial=(unsigned*)A((size_t)HBLK*256*4);
  unsigned* meta=(unsigned*)A(256);
  float* cand_v=(float*)A((size_t)CCAP*4);
  int*   cand_i=(int*)A((size_t)CCAP*4);
  int*   ci_t  =(int*)A(BCORR*4);
  int*   ci_s  =(int*)A(BCORR*4);
  int*   sel_t =(int*)A((size_t)BCORR*KK*4);
  int*   sel_s =(int*)A((size_t)BCORR*KK*4);
  float* feat_t=(float*)A((size_t)BCORR*KK*DN*4);
  float* feat_s=(float*)A((size_t)BCORR*KK*DN*4);
  float* smf   =(float*)A((size_t)BCORR*KK*KK*4);
  float* rs    =(float*)A(MN*4);
  float* csum  =(float*)A(MN*4);

  float* out=(float*)d_out;
  float* msout=out;
  float* tpout=out+(size_t)BCORR*65*65;
  float* spout=tpout+(size_t)OUTC*3;
  float* csout=spout+(size_t)OUTC*3;

  const int PB=(NPTS+255)/256;

  node_feat_kernel<<<MN,256,0,stream>>>(tgt_nf,cw,cb,tf,tt);
  node_feat_kernel<<<MN,256,0,stream>>>(src_nf,cw,cb,sfb,ssv);
  p2n_kernel<<<PB,256,0,stream>>>(src_pts,src_nx,p2n_s);
  p2n_kernel<<<PB,256,0,stream>>>(tgt_pts,tgt_nx,p2n_t);
  zero_u32_kernel<<<8,256,0,stream>>>((unsigned*)cnt_s,MN);
  zero_u32_kernel<<<8,256,0,stream>>>((unsigned*)cnt_t,MN);
  scatter_kernel<<<PB,256,0,stream>>>(p2n_s,cnt_s,list_s);
  scatter_kernel<<<PB,256,0,stream>>>(p2n_t,cnt_t,list_t);
  knn_kernel<<<MN,256,0,stream>>>(src_pts,src_nx,cnt_s,list_s,knn_s);
  knn_kernel<<<MN,256,0,stream>>>(tgt_pts,tgt_nx,cnt_t,list_t,knn_t);

  coarse_score_kernel<<<MN,256,0,stream>>>(tf,sfb,tt,ssv,cnt_t,cnt_s,Smat);
  rowsum_kernel<<<MN,256,0,stream>>>(Smat,rs);
  colsum_kernel<<<MN,256,0,stream>>>(Smat,csum);
  dualnorm_kernel<<<4096,256,0,stream>>>(Smat,rs,csum);

  hist_coarse_kernel<<<HBLK,256,0,stream>>>(Smat,MN*MN,partial);
  scan_coarse_kernel<<<1,256,0,stream>>>(partial,HBLK,BCORR,meta);
  hist_fine_kernel<<<HBLK,256,0,stream>>>(Smat,MN*MN,meta,partial);
  scan_fine_kernel<<<1,256,0,stream>>>(partial,HBLK,BCORR,meta);
  compact_kernel<<<2048,256,0,stream>>>(Smat,MN*MN,meta,cand_v,cand_i,meta+1);
  zero_u32_kernel<<<1,256,0,stream>>>((unsigned*)ci_t,BCORR);
  zero_u32_kernel<<<1,256,0,stream>>>((unsigned*)ci_s,BCORR);
  rank_coarse_kernel<<<CCAP/256,256,0,stream>>>(cand_v,cand_i,meta,ci_t,ci_s);

  gather_sel_kernel<<<BCORR,KK,0,stream>>>(ci_t,knn_t,sel_t);
  gather_sel_kernel<<<BCORR,KK,0,stream>>>(ci_s,knn_s,sel_s);
  sel_feat_kernel<<<BCORR*KK,256,0,stream>>>(sel_t,tgt_pf,fw,fb,feat_t);
  sel_feat_kernel<<<BCORR*KK,256,0,stream>>>(sel_s,src_pf,fw,fb,feat_s);

  pbuild_kernel<<<BCORR,256,0,stream>>>(feat_t,feat_s,sel_t,sel_s,alpha,msout);
  ot_kernel<<<BCORR,1024,0,stream>>>(msout,sel_t,sel_s);

  fineprep_kernel<<<BCORR,256,0,stream>>>(msout,sel_t,sel_s,smf);
  hist_coarse_kernel<<<HBLK,256,0,stream>>>(smf,BCORR*KK*KK,partial);
  scan_coarse_kernel<<<1,256,0,stream>>>(partial,HBLK,OUTC,meta);
  hist_fine_kernel<<<HBLK,256,0,stream>>>(smf,BCORR*KK*KK,meta,partial);
  scan_fine_kernel<<<1,256,0,stream>>>(partial,HBLK,OUTC,meta);
  compact_kernel<<<2048,256,0,stream>>>(smf,BCORR*KK*KK,meta,cand_v,cand_i,meta+1);
  zero_f32_kernel<<<28,256,0,stream>>>(tpout,OUTC*3*2+OUTC);
  rank_fine_kernel<<<CCAP/256,256,0,stream>>>(cand_v,cand_i,meta,sel_t,sel_s,
                                              tgt_pts,src_pts,tpout,spout,csout);
}

// Round 4
// 1237.584 us; speedup vs baseline: 1.3494x; 1.3494x over previous
//
#include <hip/hip_runtime.h>
#include <math.h>

#define NPTS 50000
#define MN 1024
#define KK 64
#define DPT 64
#define DN 256
#define BCORR 256
#define OUTC 1024
#define OTI 100
#define NEGV (-1e4f)
#define EPSV 1e-8f
#define CAPL 512
#define CCAP 16384
#define HBLK 256   // blocks for histogram passes
#define ROWP 68    // padded LDS row stride for Km (16B aligned)

// ---------------- utility ----------------
__global__ void zero_u32_kernel(unsigned* __restrict__ p, int n){
  for (int i=blockIdx.x*blockDim.x+threadIdx.x; i<n; i+=gridDim.x*blockDim.x) p[i]=0u;
}
__global__ void zero_f32_kernel(float* __restrict__ p, int n){
  for (int i=blockIdx.x*blockDim.x+threadIdx.x; i<n; i+=gridDim.x*blockDim.x) p[i]=0.0f;
}

__device__ __forceinline__ float blockReduceSum256(float v, float* red){
  int t=threadIdx.x;
  red[t]=v; __syncthreads();
  #pragma unroll
  for (int s=128;s>0;s>>=1){ if(t<s) red[t]+=red[t+s]; __syncthreads(); }
  float r=red[0]; __syncthreads();
  return r;
}

// node feats: out = l2norm(x @ W^T + b); sq = sum(out^2) (for sq_dist fidelity)
__global__ __launch_bounds__(256) void node_feat_kernel(
    const float* __restrict__ x, const float* __restrict__ W,
    const float* __restrict__ bias, float* __restrict__ out, float* __restrict__ sq){
  __shared__ float xs[DN];
  __shared__ float red[256];
  int m=blockIdx.x, i=threadIdx.x;
  xs[i]=x[m*DN+i];
  __syncthreads();
  float acc=bias[i];
  const float* wr=W+(size_t)i*DN;
  for (int k=0;k<DN;k++) acc=fmaf(wr[k],xs[k],acc);
  float ssq=blockReduceSum256(acc*acc,red);
  float o=acc/sqrtf(ssq);
  out[m*DN+i]=o;
  float s2=blockReduceSum256(o*o,red);
  if(i==0) sq[m]=s2;
}

// nearest node per point (argmin over gram-trick distance, first-min tie rule)
__global__ __launch_bounds__(256) void p2n_kernel(
    const float* __restrict__ pts, const float* __restrict__ nodes, int* __restrict__ p2n){
  __shared__ float nx[MN], ny[MN], nz[MN], nn[MN];
  for (int j=threadIdx.x;j<MN;j+=256){
    float a=nodes[j*3+0], b=nodes[j*3+1], c=nodes[j*3+2];
    nx[j]=a; ny[j]=b; nz[j]=c; nn[j]=a*a+b*b+c*c;
  }
  __syncthreads();
  int id=blockIdx.x*256+threadIdx.x;
  if (id>=NPTS) return;
  float px=pts[id*3+0], py=pts[id*3+1], pz=pts[id*3+2];
  float pp=px*px+py*py+pz*pz;
  float best=3.4e38f; int bi=0;
  for (int j=0;j<MN;j++){
    float d=pp+nn[j]-2.0f*(px*nx[j]+py*ny[j]+pz*nz[j]);
    if (d<best){best=d;bi=j;}
  }
  p2n[id]=bi;
}

__global__ __launch_bounds__(256) void scatter_kernel(
    const int* __restrict__ p2n, int* __restrict__ cnt, int* __restrict__ list){
  int id=blockIdx.x*256+threadIdx.x;
  if (id>=NPTS) return;
  int n=p2n[id];
  int t=atomicAdd(&cnt[n],1);
  if (t<CAPL) list[(size_t)n*CAPL+t]=id;
}

// per-node kNN: sort assigned points by (dist asc, idx asc), keep first 64, pad NPTS
__global__ __launch_bounds__(256) void knn_kernel(
    const float* __restrict__ pts, const float* __restrict__ nodes,
    const int* __restrict__ cnt, const int* __restrict__ list, int* __restrict__ knn){
  __shared__ float ds[CAPL];
  __shared__ int is[CAPL];
  int m=blockIdx.x;
  int c=cnt[m]; if (c>CAPL) c=CAPL;
  float ax=nodes[m*3+0], ay=nodes[m*3+1], az=nodes[m*3+2];
  float nn2=ax*ax+ay*ay+az*az;
  for (int e=threadIdx.x;e<c;e+=256){
    int p=list[(size_t)m*CAPL+e];
    float px=pts[p*3+0],py=pts[p*3+1],pz=pts[p*3+2];
    float pp=px*px+py*py+pz*pz;
    ds[e]=pp+nn2-2.0f*(px*ax+py*ay+pz*az);
    is[e]=p;
  }
  for (int k=threadIdx.x;k<KK;k+=256) knn[m*KK+k]=NPTS;
  __syncthreads();
  for (int e=threadIdx.x;e<c;e+=256){
    float d=ds[e]; int p=is[e]; int r=0;
    for (int j=0;j<c;j++){
      float dj=ds[j];
      r += (dj<d || (dj==d && is[j]<p)) ? 1 : 0;
    }
    if (r<KK) knn[m*KK+r]=p;
  }
}

// coarse scores: exp(-(tt+ss-2*dot)) masked by node validity
__global__ __launch_bounds__(256) void coarse_score_kernel(
    const float* __restrict__ tf, const float* __restrict__ sf,
    const float* __restrict__ tt, const float* __restrict__ ssv,
    const int* __restrict__ cnt_t, const int* __restrict__ cnt_s, float* __restrict__ S){
  __shared__ float ti[DN];
  int i=blockIdx.x;
  for (int k=threadIdx.x;k<DN;k+=256) ti[k]=tf[(size_t)i*DN+k];
  __syncthreads();
  int tv=cnt_t[i]>0;
  float tti=tt[i];
  for (int j=threadIdx.x;j<MN;j+=256){
    const float* sr=sf+(size_t)j*DN;
    float dot=0.0f;
    for (int k=0;k<DN;k++) dot=fmaf(ti[k],sr[k],dot);
    float d=tti+ssv[j]-2.0f*dot;
    float v=expf(-d);
    S[(size_t)i*MN+j]=(tv && cnt_s[j]>0)? v : 0.0f;
  }
}

__global__ __launch_bounds__(256) void rowsum_kernel(const float* __restrict__ S, float* __restrict__ rs){
  __shared__ float red[256];
  int i=blockIdx.x;
  float a=0;
  for (int j=threadIdx.x;j<MN;j+=256) a+=S[(size_t)i*MN+j];
  float r=blockReduceSum256(a,red);
  if (threadIdx.x==0) rs[i]=r;
}
__global__ __launch_bounds__(256) void colsum_kernel(const float* __restrict__ S, float* __restrict__ cs){
  __shared__ float red[256];
  int j=blockIdx.x;
  float a=0;
  for (int i=threadIdx.x;i<MN;i+=256) a+=S[(size_t)i*MN+j];
  float r=blockReduceSum256(a,red);
  if (threadIdx.x==0) cs[j]=r;
}
__global__ __launch_bounds__(256) void dualnorm_kernel(
    float* __restrict__ S, const float* __restrict__ rs, const float* __restrict__ cs){
  int idx=blockIdx.x*256+threadIdx.x;
  int i=idx>>10, j=idx&1023;
  float v=S[idx];
  S[idx]=(v/(rs[i]+EPSV))*(v/(cs[j]+EPSV));
}

// ---------- deterministic top-k, contention-free two-level histogram ----------
// meta layout: [0]=T (16-bit bucket threshold), [1]=candidate counter,
//              [2]=coarse bin CB, [3]=count above CB
__global__ __launch_bounds__(256) void hist_coarse_kernel(
    const float* __restrict__ arr, int n, unsigned* __restrict__ partial){
  __shared__ unsigned lh[256];
  lh[threadIdx.x]=0u; __syncthreads();
  for (int i=blockIdx.x*256+threadIdx.x; i<n; i+=gridDim.x*256){
    float v=arr[i];
    if (v>0.0f) atomicAdd(&lh[__float_as_uint(v)>>24],1u);
  }
  __syncthreads();
  partial[blockIdx.x*256+threadIdx.x]=lh[threadIdx.x];
}
__global__ __launch_bounds__(256) void scan_coarse_kernel(
    const unsigned* __restrict__ partial, int nblk, int k, unsigned* __restrict__ meta){
  __shared__ unsigned h[256];
  int t=threadIdx.x;
  unsigned a=0;
  for (int i=0;i<nblk;i++) a+=partial[(size_t)i*256+t];
  h[t]=a; __syncthreads();
  if (t==0){
    unsigned cum=0; int cb=-1; unsigned above=0;
    for (int b=255;b>=0;b--){
      if (cum+h[b] >= (unsigned)k){ cb=b; above=cum; break; }
      cum+=h[b];
    }
    if (cb<0){ cb=0; above=cum-h[0]; }   // fewer than k positives: T will be 0
    meta[2]=(unsigned)cb; meta[3]=above;
  }
}
__global__ __launch_bounds__(256) void hist_fine_kernel(
    const float* __restrict__ arr, int n, const unsigned* __restrict__ meta,
    unsigned* __restrict__ partial){
  __shared__ unsigned lh[256];
  lh[threadIdx.x]=0u; __syncthreads();
  unsigned CB=meta[2];
  for (int i=blockIdx.x*256+threadIdx.x; i<n; i+=gridDim.x*256){
    float v=arr[i];
    unsigned b=__float_as_uint(v);
    if (v>0.0f && (b>>24)==CB) atomicAdd(&lh[(b>>16)&255u],1u);
  }
  __syncthreads();
  partial[blockIdx.x*256+threadIdx.x]=lh[threadIdx.x];
}
__global__ __launch_bounds__(256) void scan_fine_kernel(
    const unsigned* __restrict__ partial, int nblk, int k, unsigned* __restrict__ meta){
  __shared__ unsigned h[256];
  int t=threadIdx.x;
  unsigned a=0;
  for (int i=0;i<nblk;i++) a+=partial[(size_t)i*256+t];
  h[t]=a; __syncthreads();
  if (t==0){
    unsigned CB=meta[2];
    unsigned cum=meta[3]; int sb=0;
    for (int b=255;b>=0;b--){
      if (cum+h[b] >= (unsigned)k){ sb=b; break; }
      cum+=h[b];
    }
    meta[0]=CB*256u+(unsigned)sb;
    meta[1]=0u;   // reset candidate counter for compact
  }
}
__global__ void compact_kernel(const float* __restrict__ arr, int n,
                               const unsigned* __restrict__ meta,
                               float* __restrict__ cv, int* __restrict__ ci,
                               unsigned* __restrict__ cnt){
  unsigned T=meta[0];
  for (int i=blockIdx.x*blockDim.x+threadIdx.x; i<n; i+=gridDim.x*blockDim.x){
    float v=arr[i];
    if (v>0.0f && (__float_as_uint(v)>>16)>=T){
      unsigned p=atomicAdd(cnt,1u);
      if (p<CCAP){ cv[p]=v; ci[p]=i; }
    }
  }
}
__global__ __launch_bounds__(256) void rank_coarse_kernel(
    const float* __restrict__ cv, const int* __restrict__ ci, const unsigned* __restrict__ meta,
    int* __restrict__ ti, int* __restrict__ si){
  int c=(int)meta[1]; if (c>CCAP) c=CCAP;
  int t=blockIdx.x*256+threadIdx.x;
  if (t>=c) return;
  float v=cv[t]; int idx=ci[t];
  int rk=0;
  for (int j=0;j<c;j++){
    float vj=cv[j]; int ij=ci[j];
    rk += (vj>v || (vj==v && ij<idx)) ? 1 : 0;
  }
  if (rk<BCORR){ ti[rk]=idx/MN; si[rk]=idx%MN; }
}
__global__ __launch_bounds__(256) void rank_fine_kernel(
    const float* __restrict__ cv, const int* __restrict__ ci, const unsigned* __restrict__ meta,
    const int* __restrict__ sel_t, const int* __restrict__ sel_s,
    const float* __restrict__ tpts, const float* __restrict__ spts,
    float* __restrict__ tp, float* __restrict__ sp, float* __restrict__ cs){
  int c=(int)meta[1]; if (c>CCAP) c=CCAP;
  int t=blockIdx.x*256+threadIdx.x;
  if (t>=c) return;
  float v=cv[t]; int idx=ci[t];
  int rk=0;
  for (int j=0;j<c;j++){
    float vj=cv[j]; int ij=ci[j];
    rk += (vj>v || (vj==v && ij<idx)) ? 1 : 0;
  }
  if (rk<OUTC){
    int b=idx>>12, r=(idx>>6)&63, cc=idx&63;
    int tpi=sel_t[b*KK+r], spi=sel_s[b*KK+cc];
    float tx=0,ty=0,tz=0,sx=0,sy=0,sz=0;
    if (tpi<NPTS){ tx=tpts[tpi*3]; ty=tpts[tpi*3+1]; tz=tpts[tpi*3+2]; }
    if (spi<NPTS){ sx=spts[spi*3]; sy=spts[spi*3+1]; sz=spts[spi*3+2]; }
    tp[rk*3+0]=tx; tp[rk*3+1]=ty; tp[rk*3+2]=tz;
    sp[rk*3+0]=sx; sp[rk*3+1]=sy; sp[rk*3+2]=sz;
    cs[rk]=v;
  }
}

// ---------- patch assembly / OT / fine ----------
__global__ void gather_sel_kernel(const int* __restrict__ ci, const int* __restrict__ knn,
                                  int* __restrict__ sel){
  int b=blockIdx.x, k=threadIdx.x;
  sel[b*KK+k]=knn[ci[b]*KK+k];
}

// selected point features: W(256x64) @ x + b; padded index -> zero vector
__global__ __launch_bounds__(256) void sel_feat_kernel(
    const int* __restrict__ sel, const float* __restrict__ ptf,
    const float* __restrict__ W, const float* __restrict__ bias, float* __restrict__ out){
  __shared__ float xs[DPT];
  int j=blockIdx.x, i=threadIdx.x;
  int p=sel[j];
  if (p==NPTS){ out[(size_t)j*DN+i]=0.0f; return; }   // block-uniform branch
  if (i<DPT) xs[i]=ptf[(size_t)p*DPT+i];
  __syncthreads();
  float acc=bias[i];
  const float* wr=W+(size_t)i*DPT;
  for (int k=0;k<DPT;k++) acc=fmaf(wr[k],xs[k],acc);
  out[(size_t)j*DN+i]=acc;
}

// build padded OT input P (65x65) per batch, with alpha dustbin + NEG masking
__global__ __launch_bounds__(256) void pbuild_kernel(
    const float* __restrict__ ft, const float* __restrict__ fs,
    const int* __restrict__ sel_t, const int* __restrict__ sel_s,
    const float* __restrict__ alpha_p, float* __restrict__ P){
  __shared__ int tm[KK], smk[KK];
  int b=blockIdx.x;
  if (threadIdx.x<KK){
    tm[threadIdx.x]= (sel_t[b*KK+threadIdx.x]!=NPTS);
    smk[threadIdx.x]= (sel_s[b*KK+threadIdx.x]!=NPTS);
  }
  __syncthreads();
  float alpha=alpha_p[0];
  const float* tb=ft+(size_t)b*KK*DN;
  const float* sb=fs+(size_t)b*KK*DN;
  float* Pb=P+(size_t)b*65*65;
  for (int e=threadIdx.x;e<65*65;e+=256){
    int r=e/65, c=e-65*r;
    bool inv=(r<KK && !tm[r]) || (c<KK && !smk[c]);
    float val;
    if (r==KK || c==KK) val=alpha;
    else {
      const float* tr=tb+(size_t)r*DN;
      const float* sr=sb+(size_t)c*DN;
      float dot=0.0f;
      for (int k=0;k<DN;k++) dot=fmaf(tr[k],sr[k],dot);
      val=dot*0.0625f;   // / sqrt(256)
    }
    Pb[e]= inv ? NEGV : val;
  }
}

// Sinkhorn in LINEAR domain: Km = exp(padded) fixed; half-step = 65x65 matvec.
// U[r]=mu[r]/sum_c Km[r,c]V[c]; V[c]=nu[c]/sum_r Km[r,c]U[r].
// Invalid rows/cols (Km row/col == 0) tracked exactly: U_inv=1/sum(V), V_inv=1/sum(U)
// (equals reference's u=-LSE(v) / v=-LSE(u)); they never feed back (Km=0) but are
// needed in the sums and in the final output u=log U, v=log V.
__global__ __launch_bounds__(1024) void ot_kernel(
    float* __restrict__ P, const int* __restrict__ sel_t, const int* __restrict__ sel_s){
  __shared__ __align__(16) float Km [65*ROWP];
  __shared__ __align__(16) float KmT[65*ROWP];
  __shared__ __align__(16) float Up[ROWP];
  __shared__ __align__(16) float Vp[ROWP];
  __shared__ float muv[65], nuv[65];
  __shared__ float rvalidf[65], cvalidf[65];
  __shared__ float uf[65], vf[65];
  __shared__ float nrm_s;
  __shared__ int nrs_s, ncs_s;
  int b=blockIdx.x, t=threadIdx.x;
  int w=t>>6, l=t&63, lane16=l&15, g=l>>4;
  float* Pg=P+(size_t)b*65*65;

  if (w==0){
    bool rv=(sel_t[b*KK+l]!=NPTS);
    unsigned long long mb=__ballot(rv);
    rvalidf[l]=rv?1.0f:0.0f;
    if (l==0){ rvalidf[64]=1.0f; nrs_s=(int)__popcll(mb); }
  } else if (w==1){
    bool cv=(sel_s[b*KK+l]!=NPTS);
    unsigned long long mb=__ballot(cv);
    cvalidf[l]=cv?1.0f:0.0f;
    if (l==0){ cvalidf[64]=1.0f; ncs_s=(int)__popcll(mb); }
  }
  for (int e=t;e<65*65;e+=1024){
    int r=e/65, c=e-65*r;
    float k=expf(Pg[e]);          // exp(NEGV)=0 exactly -> masked entries vanish
    Km[r*ROWP+c]=k; KmT[c*ROWP+r]=k;
  }
  if (t<65){
    Km [t*ROWP+65]=0.0f; Km [t*ROWP+66]=0.0f; Km [t*ROWP+67]=0.0f;
    KmT[t*ROWP+65]=0.0f; KmT[t*ROWP+66]=0.0f; KmT[t*ROWP+67]=0.0f;
  }
  if (t<ROWP){ Vp[t]=(t<65)?1.0f:0.0f; Up[t]=0.0f; }   // v0=0 -> V=1
  __syncthreads();
  if (t<65){
    float inv=1.0f/(float)(nrs_s+ncs_s);
    muv[t] = (rvalidf[t]>0.0f) ? ((t==64)? (float)ncs_s*inv : inv) : 0.0f;
    nuv[t] = (cvalidf[t]>0.0f) ? ((t==64)? (float)nrs_s*inv : inv) : 0.0f;
    if (t==0) nrm_s=-logf((float)(nrs_s+ncs_s));
  }
  __syncthreads();

  const int r0 = w + 16*g;               // rows/cols 0..63 unique per 16-lane group
  for (int it=0; it<OTI; ++it){
    // ---- u-pass ----
    {
      const float4 kv=*(const float4*)(Km + r0*ROWP + 4*lane16);
      const float4 vv=*(const float4*)(Vp + 4*lane16);
      float s = kv.x*vv.x + kv.y*vv.y + kv.z*vv.z + kv.w*vv.w;
      if (lane16==0) s = fmaf(Km[r0*ROWP+64], Vp[64], s);
      float s2=0.0f;
      if (w==0){                          // dustbin row 64 (redundant per group)
        const float4 kv2=*(const float4*)(Km + 64*ROWP + 4*lane16);
        s2 = kv2.x*vv.x + kv2.y*vv.y + kv2.z*vv.z + kv2.w*vv.w;
        if (lane16==0) s2 = fmaf(Km[64*ROWP+64], Vp[64], s2);
      }
      s += __shfl_xor(s,1);  s2 += __shfl_xor(s2,1);
      s += __shfl_xor(s,2);  s2 += __shfl_xor(s2,2);
      s += __shfl_xor(s,4);  s2 += __shfl_xor(s2,4);
      s += __shfl_xor(s,8);  s2 += __shfl_xor(s2,8);
      if (lane16==0 && rvalidf[r0]>0.0f) Up[r0]=muv[r0]/s;
      if (w==0 && l==0) Up[64]=muv[64]/s2;
      if (w==8){                          // sum(V) for invalid rows: U_inv=1/sum(V)
        float a=Vp[l];
        a+=__shfl_xor(a,1); a+=__shfl_xor(a,2); a+=__shfl_xor(a,4);
        a+=__shfl_xor(a,8); a+=__shfl_xor(a,16); a+=__shfl_xor(a,32);
        float Ui=1.0f/(a+Vp[64]);
        if (rvalidf[l]==0.0f) Up[l]=Ui;
      }
    }
    __syncthreads();
    // ---- v-pass ----
    {
      const float4 kv=*(const float4*)(KmT + r0*ROWP + 4*lane16);
      const float4 uu=*(const float4*)(Up + 4*lane16);
      float s = kv.x*uu.x + kv.y*uu.y + kv.z*uu.z + kv.w*uu.w;
      if (lane16==0) s = fmaf(KmT[r0*ROWP+64], Up[64], s);
      float s2=0.0f;
      if (w==8){                          // dustbin col 64
        const float4 kv2=*(const float4*)(KmT + 64*ROWP + 4*lane16);
        s2 = kv2.x*uu.x + kv2.y*uu.y + kv2.z*uu.z + kv2.w*uu.w;
        if (lane16==0) s2 = fmaf(KmT[64*ROWP+64], Up[64], s2);
      }
      s += __shfl_xor(s,1);  s2 += __shfl_xor(s2,1);
      s += __shfl_xor(s,2);  s2 += __shfl_xor(s2,2);
      s += __shfl_xor(s,4);  s2 += __shfl_xor(s2,4);
      s += __shfl_xor(s,8);  s2 += __shfl_xor(s2,8);
      if (lane16==0 && cvalidf[r0]>0.0f) Vp[r0]=nuv[r0]/s;
      if (w==8 && l==0) Vp[64]=nuv[64]/s2;
      if (w==0){                          // sum(U) for invalid cols: V_inv=1/sum(U)
        float a=Up[l];
        a+=__shfl_xor(a,1); a+=__shfl_xor(a,2); a+=__shfl_xor(a,4);
        a+=__shfl_xor(a,8); a+=__shfl_xor(a,16); a+=__shfl_xor(a,32);
        float Vi=1.0f/(a+Up[64]);
        if (cvalidf[l]==0.0f) Vp[l]=Vi;
      }
    }
    __syncthreads();
  }
  if (t<65){ uf[t]=logf(Up[t]); vf[t]=logf(Vp[t]); }
  __syncthreads();
  for (int e=t;e<65*65;e+=1024){
    int r=e/65, c=e-65*r;
    Pg[e]=Pg[e]+uf[r]+vf[c]-nrm_s;
  }
}

// fine prep: s=exp(ms[:, :64, :64]); mutual top-3 + threshold + masks -> sm
__global__ __launch_bounds__(256) void fineprep_kernel(
    const float* __restrict__ P, const int* __restrict__ sel_t, const int* __restrict__ sel_s,
    float* __restrict__ smout){
  __shared__ float s[KK*KK];
  __shared__ unsigned long long rowm[KK], colm[KK];
  __shared__ int tmk[KK], smk[KK];
  int b=blockIdx.x, t=threadIdx.x;
  const float* Pb=P+(size_t)b*65*65;
  for (int e=t;e<KK*KK;e+=256){
    int r=e>>6, c=e&63;
    s[e]=expf(Pb[r*65+c]);
  }
  if (t<KK){ tmk[t]=(sel_t[b*KK+t]!=NPTS); smk[t]=(sel_s[b*KK+t]!=NPTS); }
  __syncthreads();
  if (t<KK){
    float v1=-1,v2=-1,v3=-1; int i1=0,i2=0,i3=0;
    const float* row=s+t*KK;
    for (int c=0;c<KK;c++){ float v=row[c];
      if (v>v1){v3=v2;i3=i2;v2=v1;i2=i1;v1=v;i1=c;}
      else if (v>v2){v3=v2;i3=i2;v2=v;i2=c;}
      else if (v>v3){v3=v;i3=c;}
    }
    rowm[t]=(1ULL<<i1)|(1ULL<<i2)|(1ULL<<i3);
  } else if (t<2*KK){
    int c=t-KK;
    float v1=-1,v2=-1,v3=-1; int i1=0,i2=0,i3=0;
    for (int r=0;r<KK;r++){ float v=s[r*KK+c];
      if (v>v1){v3=v2;i3=i2;v2=v1;i2=i1;v1=v;i1=r;}
      else if (v>v2){v3=v2;i3=i2;v2=v;i2=r;}
      else if (v>v3){v3=v;i3=r;}
    }
    colm[c]=(1ULL<<i1)|(1ULL<<i2)|(1ULL<<i3);
  }
  __syncthreads();
  for (int e=t;e<KK*KK;e+=256){
    int r=e>>6, c=e&63;
    float v=s[e];
    bool keep = ((rowm[r]>>c)&1ULL) && ((colm[c]>>r)&1ULL) && (v>0.05f) && tmk[r] && smk[c];
    smout[(size_t)b*KK*KK+e]= keep? v : 0.0f;
  }
}

extern "C" void kernel_launch(void* const* d_in, const int* in_sizes, int n_in,
                              void* d_out, int out_size, void* d_ws, size_t ws_size,
                              hipStream_t stream){
  const float* src_pts=(const float*)d_in[0];
  const float* tgt_pts=(const float*)d_in[1];
  const float* src_pf =(const float*)d_in[2];
  const float* tgt_pf =(const float*)d_in[3];
  const float* src_nf =(const float*)d_in[4];
  const float* tgt_nf =(const float*)d_in[5];
  const float* src_nx =(const float*)d_in[6];
  const float* tgt_nx =(const float*)d_in[7];
  const float* cw=(const float*)d_in[8];
  const float* cb=(const float*)d_in[9];
  const float* fw=(const float*)d_in[10];
  const float* fb=(const float*)d_in[11];
  const float* alpha=(const float*)d_in[12];

  char* ws=(char*)d_ws;
  size_t off=0;
  auto A=[&](size_t bytes)->char*{
    char* p=ws+off; off+=(bytes+255)&~(size_t)255; return p; };

  float* tf    =(float*)A((size_t)MN*DN*4);
  float* sfb   =(float*)A((size_t)MN*DN*4);
  float* tt    =(float*)A(MN*4);
  float* ssv   =(float*)A(MN*4);
  int*   p2n_s =(int*)A((size_t)NPTS*4);
  int*   p2n_t =(int*)A((size_t)NPTS*4);
  int*   cnt_s =(int*)A(MN*4);
  int*   cnt_t =(int*)A(MN*4);
  int*   list_s=(int*)A((size_t)MN*CAPL*4);
  int*   list_t=(int*)A((size_t)MN*CAPL*4);
  int*   knn_s =(int*)A((size_t)MN*KK*4);
  int*   knn_t =(int*)A((size_t)MN*KK*4);
  float* Smat  =(float*)A((size_t)MN*MN*4);
  unsigned* partial=(unsigned*)A((size_t)HBLK*256*4);
  unsigned* meta=(unsigned*)A(256);
  float* cand_v=(float*)A((size_t)CCAP*4);
  int*   cand_i=(int*)A((size_t)CCAP*4);
  int*   ci_t  =(int*)A(BCORR*4);
  int*   ci_s  =(int*)A(BCORR*4);
  int*   sel_t =(int*)A((size_t)BCORR*KK*4);
  int*   sel_s =(int*)A((size_t)BCORR*KK*4);
  float* feat_t=(float*)A((size_t)BCORR*KK*DN*4);
  float* feat_s=(float*)A((size_t)BCORR*KK*DN*4);
  float* smf   =(float*)A((size_t)BCORR*KK*KK*4);
  float* rs    =(float*)A(MN*4);
  float* csum  =(float*)A(MN*4);

  float* out=(float*)d_out;
  float* msout=out;
  float* tpout=out+(size_t)BCORR*65*65;
  float* spout=tpout+(size_t)OUTC*3;
  float* csout=spout+(size_t)OUTC*3;

  const int PB=(NPTS+255)/256;

  node_feat_kernel<<<MN,256,0,stream>>>(tgt_nf,cw,cb,tf,tt);
  node_feat_kernel<<<MN,256,0,stream>>>(src_nf,cw,cb,sfb,ssv);
  p2n_kernel<<<PB,256,0,stream>>>(src_pts,src_nx,p2n_s);
  p2n_kernel<<<PB,256,0,stream>>>(tgt_pts,tgt_nx,p2n_t);
  zero_u32_kernel<<<8,256,0,stream>>>((unsigned*)cnt_s,MN);
  zero_u32_kernel<<<8,256,0,stream>>>((unsigned*)cnt_t,MN);
  scatter_kernel<<<PB,256,0,stream>>>(p2n_s,cnt_s,list_s);
  scatter_kernel<<<PB,256,0,stream>>>(p2n_t,cnt_t,list_t);
  knn_kernel<<<MN,256,0,stream>>>(src_pts,src_nx,cnt_s,list_s,knn_s);
  knn_kernel<<<MN,256,0,stream>>>(tgt_pts,tgt_nx,cnt_t,list_t,knn_t);

  coarse_score_kernel<<<MN,256,0,stream>>>(tf,sfb,tt,ssv,cnt_t,cnt_s,Smat);
  rowsum_kernel<<<MN,256,0,stream>>>(Smat,rs);
  colsum_kernel<<<MN,256,0,stream>>>(Smat,csum);
  dualnorm_kernel<<<4096,256,0,stream>>>(Smat,rs,csum);

  hist_coarse_kernel<<<HBLK,256,0,stream>>>(Smat,MN*MN,partial);
  scan_coarse_kernel<<<1,256,0,stream>>>(partial,HBLK,BCORR,meta);
  hist_fine_kernel<<<HBLK,256,0,stream>>>(Smat,MN*MN,meta,partial);
  scan_fine_kernel<<<1,256,0,stream>>>(partial,HBLK,BCORR,meta);
  compact_kernel<<<2048,256,0,stream>>>(Smat,MN*MN,meta,cand_v,cand_i,meta+1);
  zero_u32_kernel<<<1,256,0,stream>>>((unsigned*)ci_t,BCORR);
  zero_u32_kernel<<<1,256,0,stream>>>((unsigned*)ci_s,BCORR);
  rank_coarse_kernel<<<CCAP/256,256,0,stream>>>(cand_v,cand_i,meta,ci_t,ci_s);

  gather_sel_kernel<<<BCORR,KK,0,stream>>>(ci_t,knn_t,sel_t);
  gather_sel_kernel<<<BCORR,KK,0,stream>>>(ci_s,knn_s,sel_s);
  sel_feat_kernel<<<BCORR*KK,256,0,stream>>>(sel_t,tgt_pf,fw,fb,feat_t);
  sel_feat_kernel<<<BCORR*KK,256,0,stream>>>(sel_s,src_pf,fw,fb,feat_s);

  pbuild_kernel<<<BCORR,256,0,stream>>>(feat_t,feat_s,sel_t,sel_s,alpha,msout);
  ot_kernel<<<BCORR,1024,0,stream>>>(msout,sel_t,sel_s);

  fineprep_kernel<<<BCORR,256,0,stream>>>(msout,sel_t,sel_s,smf);
  hist_coarse_kernel<<<HBLK,256,0,stream>>>(smf,BCORR*KK*KK,partial);
  scan_coarse_kernel<<<1,256,0,stream>>>(partial,HBLK,OUTC,meta);
  hist_fine_kernel<<<HBLK,256,0,stream>>>(smf,BCORR*KK*KK,meta,partial);
  scan_fine_kernel<<<1,256,0,stream>>>(partial,HBLK,OUTC,meta);
  compact_kernel<<<2048,256,0,stream>>>(smf,BCORR*KK*KK,meta,cand_v,cand_i,meta+1);
  zero_f32_kernel<<<28,256,0,stream>>>(tpout,OUTC*3*2+OUTC);
  rank_fine_kernel<<<CCAP/256,256,0,stream>>>(cand_v,cand_i,meta,sel_t,sel_s,
                                              tgt_pts,src_pts,tpout,spout,csout);
}

// Round 5
// 1213.037 us; speedup vs baseline: 1.3767x; 1.0202x over previous
//
#include <hip/hip_runtime.h>
#include <math.h>

#define NPTS 50000
#define MN 1024
#define KK 64
#define DPT 64
#define DN 256
#define BCORR 256
#define OUTC 1024
#define OTI 100
#define NEGV (-1e4f)
#define EPSV 1e-8f
#define CAPL 512
#define CCAP 16384
#define HBLK 256   // blocks for histogram passes

// ---------------- utility ----------------
__global__ void zero_u32_kernel(unsigned* __restrict__ p, int n){
  for (int i=blockIdx.x*blockDim.x+threadIdx.x; i<n; i+=gridDim.x*blockDim.x) p[i]=0u;
}
__global__ void zero_f32_kernel(float* __restrict__ p, int n){
  for (int i=blockIdx.x*blockDim.x+threadIdx.x; i<n; i+=gridDim.x*blockDim.x) p[i]=0.0f;
}

__device__ __forceinline__ float blockReduceSum256(float v, float* red){
  int t=threadIdx.x;
  red[t]=v; __syncthreads();
  #pragma unroll
  for (int s=128;s>0;s>>=1){ if(t<s) red[t]+=red[t+s]; __syncthreads(); }
  float r=red[0]; __syncthreads();
  return r;
}

__device__ __forceinline__ float wave_sum64(float x){
  #pragma unroll
  for (int m=1;m<64;m<<=1) x+=__shfl_xor(x,m,64);
  return x;
}

// node feats: out = l2norm(x @ W^T + b); sq = sum(out^2) (for sq_dist fidelity)
__global__ __launch_bounds__(256) void node_feat_kernel(
    const float* __restrict__ x, const float* __restrict__ W,
    const float* __restrict__ bias, float* __restrict__ out, float* __restrict__ sq){
  __shared__ float xs[DN];
  __shared__ float red[256];
  int m=blockIdx.x, i=threadIdx.x;
  xs[i]=x[m*DN+i];
  __syncthreads();
  float acc=bias[i];
  const float* wr=W+(size_t)i*DN;
  for (int k=0;k<DN;k++) acc=fmaf(wr[k],xs[k],acc);
  float ssq=blockReduceSum256(acc*acc,red);
  float o=acc/sqrtf(ssq);
  out[m*DN+i]=o;
  float s2=blockReduceSum256(o*o,red);
  if(i==0) sq[m]=s2;
}

// nearest node per point (argmin over gram-trick distance, first-min tie rule)
__global__ __launch_bounds__(256) void p2n_kernel(
    const float* __restrict__ pts, const float* __restrict__ nodes, int* __restrict__ p2n){
  __shared__ float nx[MN], ny[MN], nz[MN], nn[MN];
  for (int j=threadIdx.x;j<MN;j+=256){
    float a=nodes[j*3+0], b=nodes[j*3+1], c=nodes[j*3+2];
    nx[j]=a; ny[j]=b; nz[j]=c; nn[j]=a*a+b*b+c*c;
  }
  __syncthreads();
  int id=blockIdx.x*256+threadIdx.x;
  if (id>=NPTS) return;
  float px=pts[id*3+0], py=pts[id*3+1], pz=pts[id*3+2];
  float pp=px*px+py*py+pz*pz;
  float best=3.4e38f; int bi=0;
  for (int j=0;j<MN;j++){
    float d=pp+nn[j]-2.0f*(px*nx[j]+py*ny[j]+pz*nz[j]);
    if (d<best){best=d;bi=j;}
  }
  p2n[id]=bi;
}

__global__ __launch_bounds__(256) void scatter_kernel(
    const int* __restrict__ p2n, int* __restrict__ cnt, int* __restrict__ list){
  int id=blockIdx.x*256+threadIdx.x;
  if (id>=NPTS) return;
  int n=p2n[id];
  int t=atomicAdd(&cnt[n],1);
  if (t<CAPL) list[(size_t)n*CAPL+t]=id;
}

// per-node kNN: sort assigned points by (dist asc, idx asc), keep first 64, pad NPTS
__global__ __launch_bounds__(256) void knn_kernel(
    const float* __restrict__ pts, const float* __restrict__ nodes,
    const int* __restrict__ cnt, const int* __restrict__ list, int* __restrict__ knn){
  __shared__ float ds[CAPL];
  __shared__ int is[CAPL];
  int m=blockIdx.x;
  int c=cnt[m]; if (c>CAPL) c=CAPL;
  float ax=nodes[m*3+0], ay=nodes[m*3+1], az=nodes[m*3+2];
  float nn2=ax*ax+ay*ay+az*az;
  for (int e=threadIdx.x;e<c;e+=256){
    int p=list[(size_t)m*CAPL+e];
    float px=pts[p*3+0],py=pts[p*3+1],pz=pts[p*3+2];
    float pp=px*px+py*py+pz*pz;
    ds[e]=pp+nn2-2.0f*(px*ax+py*ay+pz*az);
    is[e]=p;
  }
  for (int k=threadIdx.x;k<KK;k+=256) knn[m*KK+k]=NPTS;
  __syncthreads();
  for (int e=threadIdx.x;e<c;e+=256){
    float d=ds[e]; int p=is[e]; int r=0;
    for (int j=0;j<c;j++){
      float dj=ds[j];
      r += (dj<d || (dj==d && is[j]<p)) ? 1 : 0;
    }
    if (r<KK) knn[m*KK+r]=p;
  }
}

// coarse scores: exp(-(tt+ss-2*dot)) masked by node validity
__global__ __launch_bounds__(256) void coarse_score_kernel(
    const float* __restrict__ tf, const float* __restrict__ sf,
    const float* __restrict__ tt, const float* __restrict__ ssv,
    const int* __restrict__ cnt_t, const int* __restrict__ cnt_s, float* __restrict__ S){
  __shared__ float ti[DN];
  int i=blockIdx.x;
  for (int k=threadIdx.x;k<DN;k+=256) ti[k]=tf[(size_t)i*DN+k];
  __syncthreads();
  int tv=cnt_t[i]>0;
  float tti=tt[i];
  for (int j=threadIdx.x;j<MN;j+=256){
    const float* sr=sf+(size_t)j*DN;
    float dot=0.0f;
    for (int k=0;k<DN;k++) dot=fmaf(ti[k],sr[k],dot);
    float d=tti+ssv[j]-2.0f*dot;
    float v=expf(-d);
    S[(size_t)i*MN+j]=(tv && cnt_s[j]>0)? v : 0.0f;
  }
}

__global__ __launch_bounds__(256) void rowsum_kernel(const float* __restrict__ S, float* __restrict__ rs){
  __shared__ float red[256];
  int i=blockIdx.x;
  float a=0;
  for (int j=threadIdx.x;j<MN;j+=256) a+=S[(size_t)i*MN+j];
  float r=blockReduceSum256(a,red);
  if (threadIdx.x==0) rs[i]=r;
}
__global__ __launch_bounds__(256) void colsum_kernel(const float* __restrict__ S, float* __restrict__ cs){
  __shared__ float red[256];
  int j=blockIdx.x;
  float a=0;
  for (int i=threadIdx.x;i<MN;i+=256) a+=S[(size_t)i*MN+j];
  float r=blockReduceSum256(a,red);
  if (threadIdx.x==0) cs[j]=r;
}
__global__ __launch_bounds__(256) void dualnorm_kernel(
    float* __restrict__ S, const float* __restrict__ rs, const float* __restrict__ cs){
  int idx=blockIdx.x*256+threadIdx.x;
  int i=idx>>10, j=idx&1023;
  float v=S[idx];
  S[idx]=(v/(rs[i]+EPSV))*(v/(cs[j]+EPSV));
}

// ---------- deterministic top-k, contention-free two-level histogram ----------
// meta layout: [0]=T (16-bit bucket threshold), [1]=candidate counter,
//              [2]=coarse bin CB, [3]=count above CB
__global__ __launch_bounds__(256) void hist_coarse_kernel(
    const float* __restrict__ arr, int n, unsigned* __restrict__ partial){
  __shared__ unsigned lh[256];
  lh[threadIdx.x]=0u; __syncthreads();
  for (int i=blockIdx.x*256+threadIdx.x; i<n; i+=gridDim.x*256){
    float v=arr[i];
    if (v>0.0f) atomicAdd(&lh[__float_as_uint(v)>>24],1u);
  }
  __syncthreads();
  partial[blockIdx.x*256+threadIdx.x]=lh[threadIdx.x];
}
__global__ __launch_bounds__(256) void scan_coarse_kernel(
    const unsigned* __restrict__ partial, int nblk, int k, unsigned* __restrict__ meta){
  __shared__ unsigned h[256];
  int t=threadIdx.x;
  unsigned a=0;
  for (int i=0;i<nblk;i++) a+=partial[(size_t)i*256+t];
  h[t]=a; __syncthreads();
  if (t==0){
    unsigned cum=0; int cb=-1; unsigned above=0;
    for (int b=255;b>=0;b--){
      if (cum+h[b] >= (unsigned)k){ cb=b; above=cum; break; }
      cum+=h[b];
    }
    if (cb<0){ cb=0; above=cum-h[0]; }   // fewer than k positives: T will be 0
    meta[2]=(unsigned)cb; meta[3]=above;
  }
}
__global__ __launch_bounds__(256) void hist_fine_kernel(
    const float* __restrict__ arr, int n, const unsigned* __restrict__ meta,
    unsigned* __restrict__ partial){
  __shared__ unsigned lh[256];
  lh[threadIdx.x]=0u; __syncthreads();
  unsigned CB=meta[2];
  for (int i=blockIdx.x*256+threadIdx.x; i<n; i+=gridDim.x*256){
    float v=arr[i];
    unsigned b=__float_as_uint(v);
    if (v>0.0f && (b>>24)==CB) atomicAdd(&lh[(b>>16)&255u],1u);
  }
  __syncthreads();
  partial[blockIdx.x*256+threadIdx.x]=lh[threadIdx.x];
}
__global__ __launch_bounds__(256) void scan_fine_kernel(
    const unsigned* __restrict__ partial, int nblk, int k, unsigned* __restrict__ meta){
  __shared__ unsigned h[256];
  int t=threadIdx.x;
  unsigned a=0;
  for (int i=0;i<nblk;i++) a+=partial[(size_t)i*256+t];
  h[t]=a; __syncthreads();
  if (t==0){
    unsigned CB=meta[2];
    unsigned cum=meta[3]; int sb=0;
    for (int b=255;b>=0;b--){
      if (cum+h[b] >= (unsigned)k){ sb=b; break; }
      cum+=h[b];
    }
    meta[0]=CB*256u+(unsigned)sb;
    meta[1]=0u;   // reset candidate counter for compact
  }
}
__global__ void compact_kernel(const float* __restrict__ arr, int n,
                               const unsigned* __restrict__ meta,
                               float* __restrict__ cv, int* __restrict__ ci,
                               unsigned* __restrict__ cnt){
  unsigned T=meta[0];
  for (int i=blockIdx.x*blockDim.x+threadIdx.x; i<n; i+=gridDim.x*blockDim.x){
    float v=arr[i];
    if (v>0.0f && (__float_as_uint(v)>>16)>=T){
      unsigned p=atomicAdd(cnt,1u);
      if (p<CCAP){ cv[p]=v; ci[p]=i; }
    }
  }
}
__global__ __launch_bounds__(256) void rank_coarse_kernel(
    const float* __restrict__ cv, const int* __restrict__ ci, const unsigned* __restrict__ meta,
    int* __restrict__ ti, int* __restrict__ si){
  int c=(int)meta[1]; if (c>CCAP) c=CCAP;
  int t=blockIdx.x*256+threadIdx.x;
  if (t>=c) return;
  float v=cv[t]; int idx=ci[t];
  int rk=0;
  for (int j=0;j<c;j++){
    float vj=cv[j]; int ij=ci[j];
    rk += (vj>v || (vj==v && ij<idx)) ? 1 : 0;
  }
  if (rk<BCORR){ ti[rk]=idx/MN; si[rk]=idx%MN; }
}
__global__ __launch_bounds__(256) void rank_fine_kernel(
    const float* __restrict__ cv, const int* __restrict__ ci, const unsigned* __restrict__ meta,
    const int* __restrict__ sel_t, const int* __restrict__ sel_s,
    const float* __restrict__ tpts, const float* __restrict__ spts,
    float* __restrict__ tp, float* __restrict__ sp, float* __restrict__ cs){
  int c=(int)meta[1]; if (c>CCAP) c=CCAP;
  int t=blockIdx.x*256+threadIdx.x;
  if (t>=c) return;
  float v=cv[t]; int idx=ci[t];
  int rk=0;
  for (int j=0;j<c;j++){
    float vj=cv[j]; int ij=ci[j];
    rk += (vj>v || (vj==v && ij<idx)) ? 1 : 0;
  }
  if (rk<OUTC){
    int b=idx>>12, r=(idx>>6)&63, cc=idx&63;
    int tpi=sel_t[b*KK+r], spi=sel_s[b*KK+cc];
    float tx=0,ty=0,tz=0,sx=0,sy=0,sz=0;
    if (tpi<NPTS){ tx=tpts[tpi*3]; ty=tpts[tpi*3+1]; tz=tpts[tpi*3+2]; }
    if (spi<NPTS){ sx=spts[spi*3]; sy=spts[spi*3+1]; sz=spts[spi*3+2]; }
    tp[rk*3+0]=tx; tp[rk*3+1]=ty; tp[rk*3+2]=tz;
    sp[rk*3+0]=sx; sp[rk*3+1]=sy; sp[rk*3+2]=sz;
    cs[rk]=v;
  }
}

// ---------- patch assembly / OT / fine ----------
__global__ void gather_sel_kernel(const int* __restrict__ ci, const int* __restrict__ knn,
                                  int* __restrict__ sel){
  int b=blockIdx.x, k=threadIdx.x;
  sel[b*KK+k]=knn[ci[b]*KK+k];
}

// selected point features: W(256x64) @ x + b; padded index -> zero vector
__global__ __launch_bounds__(256) void sel_feat_kernel(
    const int* __restrict__ sel, const float* __restrict__ ptf,
    const float* __restrict__ W, const float* __restrict__ bias, float* __restrict__ out){
  __shared__ float xs[DPT];
  int j=blockIdx.x, i=threadIdx.x;
  int p=sel[j];
  if (p==NPTS){ out[(size_t)j*DN+i]=0.0f; return; }   // block-uniform branch
  if (i<DPT) xs[i]=ptf[(size_t)p*DPT+i];
  __syncthreads();
  float acc=bias[i];
  const float* wr=W+(size_t)i*DPT;
  for (int k=0;k<DPT;k++) acc=fmaf(wr[k],xs[k],acc);
  out[(size_t)j*DN+i]=acc;
}

// build padded OT input P (65x65) per batch, with alpha dustbin + NEG masking
__global__ __launch_bounds__(256) void pbuild_kernel(
    const float* __restrict__ ft, const float* __restrict__ fs,
    const int* __restrict__ sel_t, const int* __restrict__ sel_s,
    const float* __restrict__ alpha_p, float* __restrict__ P){
  __shared__ int tm[KK], smk[KK];
  int b=blockIdx.x;
  if (threadIdx.x<KK){
    tm[threadIdx.x]= (sel_t[b*KK+threadIdx.x]!=NPTS);
    smk[threadIdx.x]= (sel_s[b*KK+threadIdx.x]!=NPTS);
  }
  __syncthreads();
  float alpha=alpha_p[0];
  const float* tb=ft+(size_t)b*KK*DN;
  const float* sb=fs+(size_t)b*KK*DN;
  float* Pb=P+(size_t)b*65*65;
  for (int e=threadIdx.x;e<65*65;e+=256){
    int r=e/65, c=e-65*r;
    bool inv=(r<KK && !tm[r]) || (c<KK && !smk[c]);
    float val;
    if (r==KK || c==KK) val=alpha;
    else {
      const float* tr=tb+(size_t)r*DN;
      const float* sr=sb+(size_t)c*DN;
      float dot=0.0f;
      for (int k=0;k<DN;k++) dot=fmaf(tr[k],sr[k],dot);
      val=dot*0.0625f;   // / sqrt(256)
    }
    Pb[e]= inv ? NEGV : val;
  }
}

// Sinkhorn in LINEAR domain, ONE WAVE per batch, Km rows/cols in REGISTERS.
// Lane l owns row l (Km row in a[]) and column l (KmT row in bT[]).
// Per half-step: V broadcast via LDS uniform float4 reads; per-lane serial dot
// (no cross-lane reduce for rows 0..63). Dustbin + invalid handled by one
// wave_sum64 each. No multi-wave barriers.
__global__ __launch_bounds__(64) void ot_kernel(
    float* __restrict__ P, const int* __restrict__ sel_t, const int* __restrict__ sel_s){
  __shared__ float Ps[65*65];
  __shared__ __align__(16) float Vlds[68];
  __shared__ __align__(16) float Ulds[68];
  int b=blockIdx.x, l=threadIdx.x;
  float* Pg=P+(size_t)b*65*65;
  for (int e=l;e<65*65;e+=64) Ps[e]=Pg[e];
  bool rvalid=(sel_t[b*KK+l]!=NPTS);
  bool cvalid=(sel_s[b*KK+l]!=NPTS);
  int nr=(int)__popcll(__ballot(rvalid));
  int nc=(int)__popcll(__ballot(cvalid));
  float inv=1.0f/(float)(nr+nc);
  float nrm=-logf((float)(nr+nc));
  float mu_l=inv, nu_l=inv;                 // only used for valid lanes
  float mu64=(float)nc*inv, nu64=(float)nr*inv;
  __syncthreads();
  // register-resident kernel matrix (stride-65 scalar LDS reads: 2-way, free)
  float a[KK], bT[KK];
  #pragma unroll
  for (int c=0;c<KK;c++) a[c]=expf(Ps[l*65+c]);       // Km[l][c]
  #pragma unroll
  for (int r=0;r<KK;r++) bT[r]=expf(Ps[r*65+l]);      // Km[r][l]
  float a64=expf(Ps[l*65+64]);                        // Km[l][64]
  float b64=expf(Ps[64*65+l]);                        // Km[64][l]
  float k6464=expf(Ps[64*65+64]);                     // Km[64][64] (uniform)
  float V_l=1.0f, V64=1.0f, U_l, U64;

  for (int it=0; it<OTI; ++it){
    // ---- u-pass ----
    Vlds[l]=V_l;
    if (l==0) Vlds[64]=V64;
    __syncthreads();
    float s0=0,s1=0,s2=0,s3=0;
    #pragma unroll
    for (int c4=0;c4<16;c4++){
      float4 vv=*(const float4*)(Vlds+4*c4);          // uniform-addr broadcast
      s0=fmaf(a[4*c4+0],vv.x,s0);
      s1=fmaf(a[4*c4+1],vv.y,s1);
      s2=fmaf(a[4*c4+2],vv.z,s2);
      s3=fmaf(a[4*c4+3],vv.w,s3);
    }
    float srow=(s0+s1)+(s2+s3)+a64*V64;
    float s64=wave_sum64(b64*V_l)+k6464*V64;          // dustbin row 64
    float sv =wave_sum64(V_l)+V64;                    // sum(V) for invalid rows
    U_l = rvalid ? (mu_l/srow) : (1.0f/sv);
    U64 = mu64/s64;
    __syncthreads();
    // ---- v-pass ----
    Ulds[l]=U_l;
    if (l==0) Ulds[64]=U64;
    __syncthreads();
    float t0=0,t1=0,t2=0,t3=0;
    #pragma unroll
    for (int r4=0;r4<16;r4++){
      float4 uu=*(const float4*)(Ulds+4*r4);
      t0=fmaf(bT[4*r4+0],uu.x,t0);
      t1=fmaf(bT[4*r4+1],uu.y,t1);
      t2=fmaf(bT[4*r4+2],uu.z,t2);
      t3=fmaf(bT[4*r4+3],uu.w,t3);
    }
    float scol=(t0+t1)+(t2+t3)+b64*U64;
    float s64v=wave_sum64(a64*U_l)+k6464*U64;         // dustbin col 64
    float su  =wave_sum64(U_l)+U64;                   // sum(U) for invalid cols
    V_l = cvalid ? (nu_l/scol) : (1.0f/su);
    V64 = nu64/s64v;
    __syncthreads();
  }
  Ulds[l]=logf(U_l); Vlds[l]=logf(V_l);
  if (l==0){ Ulds[64]=logf(U64); Vlds[64]=logf(V64); }
  __syncthreads();
  for (int e=l;e<65*65;e+=64){
    int r=e/65, c=e-65*r;
    Pg[e]=Ps[e]+Ulds[r]+Vlds[c]-nrm;
  }
}

// fine prep: s=exp(ms[:, :64, :64]); mutual top-3 + threshold + masks -> sm
__global__ __launch_bounds__(256) void fineprep_kernel(
    const float* __restrict__ P, const int* __restrict__ sel_t, const int* __restrict__ sel_s,
    float* __restrict__ smout){
  __shared__ float s[KK*KK];
  __shared__ unsigned long long rowm[KK], colm[KK];
  __shared__ int tmk[KK], smk[KK];
  int b=blockIdx.x, t=threadIdx.x;
  const float* Pb=P+(size_t)b*65*65;
  for (int e=t;e<KK*KK;e+=256){
    int r=e>>6, c=e&63;
    s[e]=expf(Pb[r*65+c]);
  }
  if (t<KK){ tmk[t]=(sel_t[b*KK+t]!=NPTS); smk[t]=(sel_s[b*KK+t]!=NPTS); }
  __syncthreads();
  if (t<KK){
    float v1=-1,v2=-1,v3=-1; int i1=0,i2=0,i3=0;
    const float* row=s+t*KK;
    for (int c=0;c<KK;c++){ float v=row[c];
      if (v>v1){v3=v2;i3=i2;v2=v1;i2=i1;v1=v;i1=c;}
      else if (v>v2){v3=v2;i3=i2;v2=v;i2=c;}
      else if (v>v3){v3=v;i3=c;}
    }
    rowm[t]=(1ULL<<i1)|(1ULL<<i2)|(1ULL<<i3);
  } else if (t<2*KK){
    int c=t-KK;
    float v1=-1,v2=-1,v3=-1; int i1=0,i2=0,i3=0;
    for (int r=0;r<KK;r++){ float v=s[r*KK+c];
      if (v>v1){v3=v2;i3=i2;v2=v1;i2=i1;v1=v;i1=r;}
      else if (v>v2){v3=v2;i3=i2;v2=v;i2=r;}
      else if (v>v3){v3=v;i3=r;}
    }
    colm[c]=(1ULL<<i1)|(1ULL<<i2)|(1ULL<<i3);
  }
  __syncthreads();
  for (int e=t;e<KK*KK;e+=256){
    int r=e>>6, c=e&63;
    float v=s[e];
    bool keep = ((rowm[r]>>c)&1ULL) && ((colm[c]>>r)&1ULL) && (v>0.05f) && tmk[r] && smk[c];
    smout[(size_t)b*KK*KK+e]= keep? v : 0.0f;
  }
}

extern "C" void kernel_launch(void* const* d_in, const int* in_sizes, int n_in,
                              void* d_out, int out_size, void* d_ws, size_t ws_size,
                              hipStream_t stream){
  const float* src_pts=(const float*)d_in[0];
  const float* tgt_pts=(const float*)d_in[1];
  const float* src_pf =(const float*)d_in[2];
  const float* tgt_pf =(const float*)d_in[3];
  const float* src_nf =(const float*)d_in[4];
  const float* tgt_nf =(const float*)d_in[5];
  const float* src_nx =(const float*)d_in[6];
  const float* tgt_nx =(const float*)d_in[7];
  const float* cw=(const float*)d_in[8];
  const float* cb=(const float*)d_in[9];
  const float* fw=(const float*)d_in[10];
  const float* fb=(const float*)d_in[11];
  const float* alpha=(const float*)d_in[12];

  char* ws=(char*)d_ws;
  size_t off=0;
  auto A=[&](size_t bytes)->char*{
    char* p=ws+off; off+=(bytes+255)&~(size_t)255; return p; };

  float* tf    =(float*)A((size_t)MN*DN*4);
  float* sfb   =(float*)A((size_t)MN*DN*4);
  float* tt    =(float*)A(MN*4);
  float* ssv   =(float*)A(MN*4);
  int*   p2n_s =(int*)A((size_t)NPTS*4);
  int*   p2n_t =(int*)A((size_t)NPTS*4);
  int*   cnt_s =(int*)A(MN*4);
  int*   cnt_t =(int*)A(MN*4);
  int*   list_s=(int*)A((size_t)MN*CAPL*4);
  int*   list_t=(int*)A((size_t)MN*CAPL*4);
  int*   knn_s =(int*)A((size_t)MN*KK*4);
  int*   knn_t =(int*)A((size_t)MN*KK*4);
  float* Smat  =(float*)A((size_t)MN*MN*4);
  unsigned* partial=(unsigned*)A((size_t)HBLK*256*4);
  unsigned* meta=(unsigned*)A(256);
  float* cand_v=(float*)A((size_t)CCAP*4);
  int*   cand_i=(int*)A((size_t)CCAP*4);
  int*   ci_t  =(int*)A(BCORR*4);
  int*   ci_s  =(int*)A(BCORR*4);
  int*   sel_t =(int*)A((size_t)BCORR*KK*4);
  int*   sel_s =(int*)A((size_t)BCORR*KK*4);
  float* feat_t=(float*)A((size_t)BCORR*KK*DN*4);
  float* feat_s=(float*)A((size_t)BCORR*KK*DN*4);
  float* smf   =(float*)A((size_t)BCORR*KK*KK*4);
  float* rs    =(float*)A(MN*4);
  float* csum  =(float*)A(MN*4);

  float* out=(float*)d_out;
  float* msout=out;
  float* tpout=out+(size_t)BCORR*65*65;
  float* spout=tpout+(size_t)OUTC*3;
  float* csout=spout+(size_t)OUTC*3;

  const int PB=(NPTS+255)/256;

  node_feat_kernel<<<MN,256,0,stream>>>(tgt_nf,cw,cb,tf,tt);
  node_feat_kernel<<<MN,256,0,stream>>>(src_nf,cw,cb,sfb,ssv);
  p2n_kernel<<<PB,256,0,stream>>>(src_pts,src_nx,p2n_s);
  p2n_kernel<<<PB,256,0,stream>>>(tgt_pts,tgt_nx,p2n_t);
  zero_u32_kernel<<<8,256,0,stream>>>((unsigned*)cnt_s,MN);
  zero_u32_kernel<<<8,256,0,stream>>>((unsigned*)cnt_t,MN);
  scatter_kernel<<<PB,256,0,stream>>>(p2n_s,cnt_s,list_s);
  scatter_kernel<<<PB,256,0,stream>>>(p2n_t,cnt_t,list_t);
  knn_kernel<<<MN,256,0,stream>>>(src_pts,src_nx,cnt_s,list_s,knn_s);
  knn_kernel<<<MN,256,0,stream>>>(tgt_pts,tgt_nx,cnt_t,list_t,knn_t);

  coarse_score_kernel<<<MN,256,0,stream>>>(tf,sfb,tt,ssv,cnt_t,cnt_s,Smat);
  rowsum_kernel<<<MN,256,0,stream>>>(Smat,rs);
  colsum_kernel<<<MN,256,0,stream>>>(Smat,csum);
  dualnorm_kernel<<<4096,256,0,stream>>>(Smat,rs,csum);

  hist_coarse_kernel<<<HBLK,256,0,stream>>>(Smat,MN*MN,partial);
  scan_coarse_kernel<<<1,256,0,stream>>>(partial,HBLK,BCORR,meta);
  hist_fine_kernel<<<HBLK,256,0,stream>>>(Smat,MN*MN,meta,partial);
  scan_fine_kernel<<<1,256,0,stream>>>(partial,HBLK,BCORR,meta);
  compact_kernel<<<2048,256,0,stream>>>(Smat,MN*MN,meta,cand_v,cand_i,meta+1);
  zero_u32_kernel<<<1,256,0,stream>>>((unsigned*)ci_t,BCORR);
  zero_u32_kernel<<<1,256,0,stream>>>((unsigned*)ci_s,BCORR);
  rank_coarse_kernel<<<CCAP/256,256,0,stream>>>(cand_v,cand_i,meta,ci_t,ci_s);

  gather_sel_kernel<<<BCORR,KK,0,stream>>>(ci_t,knn_t,sel_t);
  gather_sel_kernel<<<BCORR,KK,0,stream>>>(ci_s,knn_s,sel_s);
  sel_feat_kernel<<<BCORR*KK,256,0,stream>>>(sel_t,tgt_pf,fw,fb,feat_t);
  sel_feat_kernel<<<BCORR*KK,256,0,stream>>>(sel_s,src_pf,fw,fb,feat_s);

  pbuild_kernel<<<BCORR,256,0,stream>>>(feat_t,feat_s,sel_t,sel_s,alpha,msout);
  ot_kernel<<<BCORR,64,0,stream>>>(msout,sel_t,sel_s);

  fineprep_kernel<<<BCORR,256,0,stream>>>(msout,sel_t,sel_s,smf);
  hist_coarse_kernel<<<HBLK,256,0,stream>>>(smf,BCORR*KK*KK,partial);
  scan_coarse_kernel<<<1,256,0,stream>>>(partial,HBLK,OUTC,meta);
  hist_fine_kernel<<<HBLK,256,0,stream>>>(smf,BCORR*KK*KK,meta,partial);
  scan_fine_kernel<<<1,256,0,stream>>>(partial,HBLK,OUTC,meta);
  compact_kernel<<<2048,256,0,stream>>>(smf,BCORR*KK*KK,meta,cand_v,cand_i,meta+1);
  zero_f32_kernel<<<28,256,0,stream>>>(tpout,OUTC*3*2+OUTC);
  rank_fine_kernel<<<CCAP/256,256,0,stream>>>(cand_v,cand_i,meta,sel_t,sel_s,
                                              tgt_pts,src_pts,tpout,spout,csout);
}

// Round 6
// 822.570 us; speedup vs baseline: 2.0302x; 1.4747x over previous
//
#include <hip/hip_runtime.h>
#include <math.h>

#define NPTS 50000
#define MN 1024
#define KK 64
#define DPT 64
#define DN 256
#define BCORR 256
#define OUTC 1024
#define OTI 100
#define NEGV (-1e4f)
#define EPSV 1e-8f
#define CAPL 512
#define CCAP 16384
#define HBLK 256   // blocks for histogram passes

// ---------------- utility ----------------
__global__ void zero_u32_kernel(unsigned* __restrict__ p, int n){
  for (int i=blockIdx.x*blockDim.x+threadIdx.x; i<n; i+=gridDim.x*blockDim.x) p[i]=0u;
}
__global__ void zero_f32_kernel(float* __restrict__ p, int n){
  for (int i=blockIdx.x*blockDim.x+threadIdx.x; i<n; i+=gridDim.x*blockDim.x) p[i]=0.0f;
}

__device__ __forceinline__ float blockReduceSum256(float v, float* red){
  int t=threadIdx.x;
  red[t]=v; __syncthreads();
  #pragma unroll
  for (int s=128;s>0;s>>=1){ if(t<s) red[t]+=red[t+s]; __syncthreads(); }
  float r=red[0]; __syncthreads();
  return r;
}

// node feats: out = l2norm(x @ W^T + b); sq = sum(out^2) (for sq_dist fidelity)
__global__ __launch_bounds__(256) void node_feat_kernel(
    const float* __restrict__ x, const float* __restrict__ W,
    const float* __restrict__ bias, float* __restrict__ out, float* __restrict__ sq){
  __shared__ float xs[DN];
  __shared__ float red[256];
  int m=blockIdx.x, i=threadIdx.x;
  xs[i]=x[m*DN+i];
  __syncthreads();
  float acc=bias[i];
  const float* wr=W+(size_t)i*DN;
  for (int k=0;k<DN;k++) acc=fmaf(wr[k],xs[k],acc);
  float ssq=blockReduceSum256(acc*acc,red);
  float o=acc/sqrtf(ssq);
  out[m*DN+i]=o;
  float s2=blockReduceSum256(o*o,red);
  if(i==0) sq[m]=s2;
}

// nearest node per point (argmin over gram-trick distance, first-min tie rule)
__global__ __launch_bounds__(256) void p2n_kernel(
    const float* __restrict__ pts, const float* __restrict__ nodes, int* __restrict__ p2n){
  __shared__ float nx[MN], ny[MN], nz[MN], nn[MN];
  for (int j=threadIdx.x;j<MN;j+=256){
    float a=nodes[j*3+0], b=nodes[j*3+1], c=nodes[j*3+2];
    nx[j]=a; ny[j]=b; nz[j]=c; nn[j]=a*a+b*b+c*c;
  }
  __syncthreads();
  int id=blockIdx.x*256+threadIdx.x;
  if (id>=NPTS) return;
  float px=pts[id*3+0], py=pts[id*3+1], pz=pts[id*3+2];
  float pp=px*px+py*py+pz*pz;
  float best=3.4e38f; int bi=0;
  for (int j=0;j<MN;j++){
    float d=pp+nn[j]-2.0f*(px*nx[j]+py*ny[j]+pz*nz[j]);
    if (d<best){best=d;bi=j;}
  }
  p2n[id]=bi;
}

__global__ __launch_bounds__(256) void scatter_kernel(
    const int* __restrict__ p2n, int* __restrict__ cnt, int* __restrict__ list){
  int id=blockIdx.x*256+threadIdx.x;
  if (id>=NPTS) return;
  int n=p2n[id];
  int t=atomicAdd(&cnt[n],1);
  if (t<CAPL) list[(size_t)n*CAPL+t]=id;
}

// per-node kNN: sort assigned points by (dist asc, idx asc), keep first 64, pad NPTS
__global__ __launch_bounds__(256) void knn_kernel(
    const float* __restrict__ pts, const float* __restrict__ nodes,
    const int* __restrict__ cnt, const int* __restrict__ list, int* __restrict__ knn){
  __shared__ float ds[CAPL];
  __shared__ int is[CAPL];
  int m=blockIdx.x;
  int c=cnt[m]; if (c>CAPL) c=CAPL;
  float ax=nodes[m*3+0], ay=nodes[m*3+1], az=nodes[m*3+2];
  float nn2=ax*ax+ay*ay+az*az;
  for (int e=threadIdx.x;e<c;e+=256){
    int p=list[(size_t)m*CAPL+e];
    float px=pts[p*3+0],py=pts[p*3+1],pz=pts[p*3+2];
    float pp=px*px+py*py+pz*pz;
    ds[e]=pp+nn2-2.0f*(px*ax+py*ay+pz*az);
    is[e]=p;
  }
  for (int k=threadIdx.x;k<KK;k+=256) knn[m*KK+k]=NPTS;
  __syncthreads();
  for (int e=threadIdx.x;e<c;e+=256){
    float d=ds[e]; int p=is[e]; int r=0;
    for (int j=0;j<c;j++){
      float dj=ds[j];
      r += (dj<d || (dj==d && is[j]<p)) ? 1 : 0;
    }
    if (r<KK) knn[m*KK+r]=p;
  }
}

// coarse scores as tiled GEMM: S[i][j] = valid ? exp(-(tt_i+ss_j-2*dot)) : 0
// grid 256 = 16x16 tiles of 64x64, k=256 in 4 chunks, 4x4 register blocking.
__global__ __launch_bounds__(256) void coarse_score_kernel(
    const float* __restrict__ tf, const float* __restrict__ sf,
    const float* __restrict__ tt, const float* __restrict__ ssv,
    const int* __restrict__ cnt_t, const int* __restrict__ cnt_s, float* __restrict__ S){
  __shared__ float tas[64][64];   // [k][r]
  __shared__ float sbs[64][64];   // [k][c]
  __shared__ float tta[64], ssa[64], tva[64], sva[64];
  int bi=blockIdx.x>>4, bj=blockIdx.x&15;
  int t=threadIdx.x, r=t&63, kq=t>>6, tx=t&15, ty=t>>4;
  if (kq==0){ tta[r]=tt[bi*64+r]; tva[r]=(cnt_t[bi*64+r]>0)?1.f:0.f; }
  if (kq==1){ ssa[r]=ssv[bj*64+r]; sva[r]=(cnt_s[bj*64+r]>0)?1.f:0.f; }
  float acc[4][4]={};
  const float* ta=tf+((size_t)bi*64)*DN;
  const float* sa=sf+((size_t)bj*64)*DN;
  for (int kc=0;kc<DN;kc+=64){
    __syncthreads();
    const float* tr_=ta+(size_t)r*DN+kc+kq*16;
    const float* sr_=sa+(size_t)r*DN+kc+kq*16;
    #pragma unroll
    for (int j4=0;j4<4;j4++){
      float4 v=*(const float4*)(tr_+4*j4);
      tas[kq*16+4*j4+0][r]=v.x; tas[kq*16+4*j4+1][r]=v.y;
      tas[kq*16+4*j4+2][r]=v.z; tas[kq*16+4*j4+3][r]=v.w;
      float4 w=*(const float4*)(sr_+4*j4);
      sbs[kq*16+4*j4+0][r]=w.x; sbs[kq*16+4*j4+1][r]=w.y;
      sbs[kq*16+4*j4+2][r]=w.z; sbs[kq*16+4*j4+3][r]=w.w;
    }
    __syncthreads();
    #pragma unroll
    for (int kk=0;kk<64;kk++){
      float4 a4=*(const float4*)(&tas[kk][4*ty]);
      float4 b4=*(const float4*)(&sbs[kk][4*tx]);
      float av[4]={a4.x,a4.y,a4.z,a4.w};
      float bv[4]={b4.x,b4.y,b4.z,b4.w};
      #pragma unroll
      for (int i=0;i<4;i++)
        #pragma unroll
        for (int j=0;j<4;j++) acc[i][j]=fmaf(av[i],bv[j],acc[i][j]);
    }
  }
  __syncthreads();
  #pragma unroll
  for (int i=0;i<4;i++){
    int rr=4*ty+i;
    #pragma unroll
    for (int j=0;j<4;j++){
      int cc=4*tx+j;
      float d=tta[rr]+ssa[cc]-2.0f*acc[i][j];
      float v=expf(-d);
      S[(size_t)(bi*64+rr)*MN + bj*64+cc]=(tva[rr]>0.f && sva[cc]>0.f)? v:0.0f;
    }
  }
}

__global__ __launch_bounds__(256) void rowsum_kernel(const float* __restrict__ S, float* __restrict__ rs){
  __shared__ float red[256];
  int i=blockIdx.x;
  float a=0;
  for (int j=threadIdx.x;j<MN;j+=256) a+=S[(size_t)i*MN+j];
  float r=blockReduceSum256(a,red);
  if (threadIdx.x==0) rs[i]=r;
}
__global__ __launch_bounds__(256) void colsum_kernel(const float* __restrict__ S, float* __restrict__ cs){
  __shared__ float red[256];
  int j=blockIdx.x;
  float a=0;
  for (int i=threadIdx.x;i<MN;i+=256) a+=S[(size_t)i*MN+j];
  float r=blockReduceSum256(a,red);
  if (threadIdx.x==0) cs[j]=r;
}
__global__ __launch_bounds__(256) void dualnorm_kernel(
    float* __restrict__ S, const float* __restrict__ rs, const float* __restrict__ cs){
  int idx=blockIdx.x*256+threadIdx.x;
  int i=idx>>10, j=idx&1023;
  float v=S[idx];
  S[idx]=(v/(rs[i]+EPSV))*(v/(cs[j]+EPSV));
}

// ---------- deterministic top-k, contention-free two-level histogram ----------
__global__ __launch_bounds__(256) void hist_coarse_kernel(
    const float* __restrict__ arr, int n, unsigned* __restrict__ partial){
  __shared__ unsigned lh[256];
  lh[threadIdx.x]=0u; __syncthreads();
  for (int i=blockIdx.x*256+threadIdx.x; i<n; i+=gridDim.x*256){
    float v=arr[i];
    if (v>0.0f) atomicAdd(&lh[__float_as_uint(v)>>24],1u);
  }
  __syncthreads();
  partial[blockIdx.x*256+threadIdx.x]=lh[threadIdx.x];
}
__global__ __launch_bounds__(256) void scan_coarse_kernel(
    const unsigned* __restrict__ partial, int nblk, int k, unsigned* __restrict__ meta){
  __shared__ unsigned h[256];
  int t=threadIdx.x;
  unsigned a=0;
  for (int i=0;i<nblk;i++) a+=partial[(size_t)i*256+t];
  h[t]=a; __syncthreads();
  if (t==0){
    unsigned cum=0; int cb=-1; unsigned above=0;
    for (int b=255;b>=0;b--){
      if (cum+h[b] >= (unsigned)k){ cb=b; above=cum; break; }
      cum+=h[b];
    }
    if (cb<0){ cb=0; above=cum-h[0]; }
    meta[2]=(unsigned)cb; meta[3]=above;
  }
}
__global__ __launch_bounds__(256) void hist_fine_kernel(
    const float* __restrict__ arr, int n, const unsigned* __restrict__ meta,
    unsigned* __restrict__ partial){
  __shared__ unsigned lh[256];
  lh[threadIdx.x]=0u; __syncthreads();
  unsigned CB=meta[2];
  for (int i=blockIdx.x*256+threadIdx.x; i<n; i+=gridDim.x*256){
    float v=arr[i];
    unsigned b=__float_as_uint(v);
    if (v>0.0f && (b>>24)==CB) atomicAdd(&lh[(b>>16)&255u],1u);
  }
  __syncthreads();
  partial[blockIdx.x*256+threadIdx.x]=lh[threadIdx.x];
}
__global__ __launch_bounds__(256) void scan_fine_kernel(
    const unsigned* __restrict__ partial, int nblk, int k, unsigned* __restrict__ meta){
  __shared__ unsigned h[256];
  int t=threadIdx.x;
  unsigned a=0;
  for (int i=0;i<nblk;i++) a+=partial[(size_t)i*256+t];
  h[t]=a; __syncthreads();
  if (t==0){
    unsigned CB=meta[2];
    unsigned cum=meta[3]; int sb=0;
    for (int b=255;b>=0;b--){
      if (cum+h[b] >= (unsigned)k){ sb=b; break; }
      cum+=h[b];
    }
    meta[0]=CB*256u+(unsigned)sb;
    meta[1]=0u;
  }
}
__global__ void compact_kernel(const float* __restrict__ arr, int n,
                               const unsigned* __restrict__ meta,
                               float* __restrict__ cv, int* __restrict__ ci,
                               unsigned* __restrict__ cnt){
  unsigned T=meta[0];
  for (int i=blockIdx.x*blockDim.x+threadIdx.x; i<n; i+=gridDim.x*blockDim.x){
    float v=arr[i];
    if (v>0.0f && (__float_as_uint(v)>>16)>=T){
      unsigned p=atomicAdd(cnt,1u);
      if (p<CCAP){ cv[p]=v; ci[p]=i; }
    }
  }
}
__global__ __launch_bounds__(256) void rank_coarse_kernel(
    const float* __restrict__ cv, const int* __restrict__ ci, const unsigned* __restrict__ meta,
    int* __restrict__ ti, int* __restrict__ si){
  int c=(int)meta[1]; if (c>CCAP) c=CCAP;
  int t=blockIdx.x*256+threadIdx.x;
  if (t>=c) return;
  float v=cv[t]; int idx=ci[t];
  int rk=0;
  for (int j=0;j<c;j++){
    float vj=cv[j]; int ij=ci[j];
    rk += (vj>v || (vj==v && ij<idx)) ? 1 : 0;
  }
  if (rk<BCORR){ ti[rk]=idx/MN; si[rk]=idx%MN; }
}
__global__ __launch_bounds__(256) void rank_fine_kernel(
    const float* __restrict__ cv, const int* __restrict__ ci, const unsigned* __restrict__ meta,
    const int* __restrict__ sel_t, const int* __restrict__ sel_s,
    const float* __restrict__ tpts, const float* __restrict__ spts,
    float* __restrict__ tp, float* __restrict__ sp, float* __restrict__ cs){
  int c=(int)meta[1]; if (c>CCAP) c=CCAP;
  int t=blockIdx.x*256+threadIdx.x;
  if (t>=c) return;
  float v=cv[t]; int idx=ci[t];
  int rk=0;
  for (int j=0;j<c;j++){
    float vj=cv[j]; int ij=ci[j];
    rk += (vj>v || (vj==v && ij<idx)) ? 1 : 0;
  }
  if (rk<OUTC){
    int b=idx>>12, r=(idx>>6)&63, cc=idx&63;
    int tpi=sel_t[b*KK+r], spi=sel_s[b*KK+cc];
    float tx=0,ty=0,tz=0,sx=0,sy=0,sz=0;
    if (tpi<NPTS){ tx=tpts[tpi*3]; ty=tpts[tpi*3+1]; tz=tpts[tpi*3+2]; }
    if (spi<NPTS){ sx=spts[spi*3]; sy=spts[spi*3+1]; sz=spts[spi*3+2]; }
    tp[rk*3+0]=tx; tp[rk*3+1]=ty; tp[rk*3+2]=tz;
    sp[rk*3+0]=sx; sp[rk*3+1]=sy; sp[rk*3+2]=sz;
    cs[rk]=v;
  }
}

// ---------- patch assembly / OT / fine ----------
__global__ void gather_sel_kernel(const int* __restrict__ ci, const int* __restrict__ knn,
                                  int* __restrict__ sel){
  int b=blockIdx.x, k=threadIdx.x;
  sel[b*KK+k]=knn[ci[b]*KK+k];
}

// gathered point features as tiled GEMM: out (16384x256) = X(16384x64) @ W^T + b
// grid 1024 = 256 row-tiles x 4 out-tiles; pad rows (sel==NPTS) -> zero vector.
__global__ __launch_bounds__(256) void sel_feat_kernel(
    const int* __restrict__ sel, const float* __restrict__ ptf,
    const float* __restrict__ W, const float* __restrict__ bias, float* __restrict__ out){
  __shared__ float Xs[64][64];   // [k][r]
  __shared__ float Ws[64][64];   // [k][o]
  __shared__ float pvf[64];
  int bj=blockIdx.x>>2, bo=blockIdx.x&3;
  int t=threadIdx.x, r=t&63, kq=t>>6, tx=t&15, ty=t>>4;
  int p=sel[bj*64+r];
  if (kq==0) pvf[r]=(p!=NPTS)?1.f:0.f;
  const float* xr=ptf+(size_t)p*DPT+kq*16;
  #pragma unroll
  for (int j4=0;j4<4;j4++){
    float4 v=(p==NPTS)? make_float4(0.f,0.f,0.f,0.f) : *(const float4*)(xr+4*j4);
    Xs[kq*16+4*j4+0][r]=v.x; Xs[kq*16+4*j4+1][r]=v.y;
    Xs[kq*16+4*j4+2][r]=v.z; Xs[kq*16+4*j4+3][r]=v.w;
  }
  const float* wr=W+(size_t)(bo*64+r)*DPT+kq*16;
  #pragma unroll
  for (int j4=0;j4<4;j4++){
    float4 w=*(const float4*)(wr+4*j4);
    Ws[kq*16+4*j4+0][r]=w.x; Ws[kq*16+4*j4+1][r]=w.y;
    Ws[kq*16+4*j4+2][r]=w.z; Ws[kq*16+4*j4+3][r]=w.w;
  }
  __syncthreads();
  float acc[4][4]={};
  #pragma unroll
  for (int kk=0;kk<64;kk++){
    float4 a4=*(const float4*)(&Xs[kk][4*ty]);
    float4 w4=*(const float4*)(&Ws[kk][4*tx]);
    float av[4]={a4.x,a4.y,a4.z,a4.w};
    float wv[4]={w4.x,w4.y,w4.z,w4.w};
    #pragma unroll
    for (int i=0;i<4;i++)
      #pragma unroll
      for (int j=0;j<4;j++) acc[i][j]=fmaf(av[i],wv[j],acc[i][j]);
  }
  #pragma unroll
  for (int i=0;i<4;i++){
    int rr=4*ty+i;
    #pragma unroll
    for (int j=0;j<4;j++){
      int oo=4*tx+j;
      float v=acc[i][j]+bias[bo*64+oo];
      out[(size_t)(bj*64+rr)*DN + bo*64+oo]= (pvf[rr]>0.f)? v : 0.0f;
    }
  }
}

// OT input P (65x65) per batch as tiled GEMM (64x64x256) + dustbin/mask epilogue
__global__ __launch_bounds__(256) void pbuild_kernel(
    const float* __restrict__ ft, const float* __restrict__ fs,
    const int* __restrict__ sel_t, const int* __restrict__ sel_s,
    const float* __restrict__ alpha_p, float* __restrict__ P){
  __shared__ float tas[64][64];   // [k][r]
  __shared__ float sbs[64][64];   // [k][c]
  __shared__ float tmv[64], smv[64];
  int b=blockIdx.x, t=threadIdx.x;
  int r=t&63, kq=t>>6, tx=t&15, ty=t>>4;
  if (kq==0) tmv[r]=(sel_t[b*KK+r]!=NPTS)?1.f:0.f;
  if (kq==1) smv[r]=(sel_s[b*KK+r]!=NPTS)?1.f:0.f;
  float acc[4][4]={};
  const float* tb=ft+(size_t)b*KK*DN;
  const float* sb=fs+(size_t)b*KK*DN;
  for (int kc=0;kc<DN;kc+=64){
    __syncthreads();
    const float* tr_=tb+(size_t)r*DN+kc+kq*16;
    const float* sr_=sb+(size_t)r*DN+kc+kq*16;
    #pragma unroll
    for (int j4=0;j4<4;j4++){
      float4 v=*(const float4*)(tr_+4*j4);
      tas[kq*16+4*j4+0][r]=v.x; tas[kq*16+4*j4+1][r]=v.y;
      tas[kq*16+4*j4+2][r]=v.z; tas[kq*16+4*j4+3][r]=v.w;
      float4 w=*(const float4*)(sr_+4*j4);
      sbs[kq*16+4*j4+0][r]=w.x; sbs[kq*16+4*j4+1][r]=w.y;
      sbs[kq*16+4*j4+2][r]=w.z; sbs[kq*16+4*j4+3][r]=w.w;
    }
    __syncthreads();
    #pragma unroll
    for (int kk=0;kk<64;kk++){
      float4 a4=*(const float4*)(&tas[kk][4*ty]);
      float4 b4=*(const float4*)(&sbs[kk][4*tx]);
      float av[4]={a4.x,a4.y,a4.z,a4.w};
      float bv[4]={b4.x,b4.y,b4.z,b4.w};
      #pragma unroll
      for (int i=0;i<4;i++)
        #pragma unroll
        for (int j=0;j<4;j++) acc[i][j]=fmaf(av[i],bv[j],acc[i][j]);
    }
  }
  __syncthreads();
  float alpha=alpha_p[0];
  float* Pb=P+(size_t)b*65*65;
  #pragma unroll
  for (int i=0;i<4;i++){
    int rr=4*ty+i;
    bool tok=tmv[rr]>0.f;
    #pragma unroll
    for (int j=0;j<4;j++){
      int cc=4*tx+j;
      bool invm=(!tok)||(smv[cc]<=0.f);
      Pb[rr*65+cc]= invm ? NEGV : acc[i][j]*0.0625f;
    }
  }
  if (t<64){
    Pb[64*65+t]=(smv[t]<=0.f)? NEGV : alpha;
    Pb[t*65+64]=(tmv[t]<=0.f)? NEGV : alpha;
  }
  if (t==64) Pb[64*65+64]=alpha;
}

// Sinkhorn in LINEAR domain, one wave per batch, Km rows/cols in registers.
// All cross-lane reductions via LDS-broadcast redundant sums (no shfl trees):
// lane l writes V_l and b64*V_l; every lane reads all 64 back as uniform float4
// broadcasts and accumulates row-dot / dustbin-dot / sum(V) in parallel chains.
__global__ __launch_bounds__(64) void ot_kernel(
    float* __restrict__ P, const int* __restrict__ sel_t, const int* __restrict__ sel_s){
  __shared__ float Ps[65*65];
  __shared__ __align__(16) float Vlds[64];
  __shared__ __align__(16) float Ulds[64];
  __shared__ __align__(16) float Pv[64];
  __shared__ __align__(16) float Pu[64];
  __shared__ float uf[65], vf[65];
  int b=blockIdx.x, l=threadIdx.x;
  float* Pg=P+(size_t)b*65*65;
  for (int e=l;e<65*65;e+=64) Ps[e]=Pg[e];
  bool rvalid=(sel_t[b*KK+l]!=NPTS);
  bool cvalid=(sel_s[b*KK+l]!=NPTS);
  int nr=(int)__popcll(__ballot(rvalid));
  int nc=(int)__popcll(__ballot(cvalid));
  float inv=1.0f/(float)(nr+nc);
  float nrm=-logf((float)(nr+nc));
  float mu_l=inv, nu_l=inv;
  float mu64=(float)nc*inv, nu64=(float)nr*inv;
  __syncthreads();
  float a[KK], bT[KK];
  #pragma unroll
  for (int c=0;c<KK;c++) a[c]=expf(Ps[l*65+c]);       // Km[l][c]
  #pragma unroll
  for (int r=0;r<KK;r++) bT[r]=expf(Ps[r*65+l]);      // Km[r][l]
  float a64=expf(Ps[l*65+64]);                        // Km[l][64]
  float b64=expf(Ps[64*65+l]);                        // Km[64][l]
  float k6464=expf(Ps[64*65+64]);                     // Km[64][64] (uniform)
  float V_l=1.0f, V64=1.0f, U_l, U64;                 // V64/U64 redundant per-lane

  for (int it=0; it<OTI; ++it){
    // ---- u-pass ----
    Vlds[l]=V_l; Pv[l]=b64*V_l;
    __syncthreads();
    float s0=0,s1=0,s2=0,s3=0, d0=0,d1=0,d2=0,d3=0, z0=0,z1=0,z2=0,z3=0;
    #pragma unroll
    for (int c4=0;c4<16;c4++){
      float4 vv=*(const float4*)(Vlds+4*c4);          // uniform broadcast
      float4 pp=*(const float4*)(Pv+4*c4);
      s0=fmaf(a[4*c4+0],vv.x,s0); s1=fmaf(a[4*c4+1],vv.y,s1);
      s2=fmaf(a[4*c4+2],vv.z,s2); s3=fmaf(a[4*c4+3],vv.w,s3);
      d0+=pp.x; d1+=pp.y; d2+=pp.z; d3+=pp.w;
      z0+=vv.x; z1+=vv.y; z2+=vv.z; z3+=vv.w;
    }
    float srow=(s0+s1)+(s2+s3)+a64*V64;
    float s64 =(d0+d1)+(d2+d3)+k6464*V64;             // dustbin row dot
    float sv  =(z0+z1)+(z2+z3)+V64;                   // sum(V) for invalid rows
    U_l = rvalid ? (mu_l/srow) : (1.0f/sv);
    U64 = mu64/s64;
    __syncthreads();
    // ---- v-pass ----
    Ulds[l]=U_l; Pu[l]=a64*U_l;
    __syncthreads();
    float t0=0,t1=0,t2=0,t3=0, e0=0,e1=0,e2=0,e3=0, y0=0,y1=0,y2=0,y3=0;
    #pragma unroll
    for (int r4=0;r4<16;r4++){
      float4 uu=*(const float4*)(Ulds+4*r4);
      float4 qq=*(const float4*)(Pu+4*r4);
      t0=fmaf(bT[4*r4+0],uu.x,t0); t1=fmaf(bT[4*r4+1],uu.y,t1);
      t2=fmaf(bT[4*r4+2],uu.z,t2); t3=fmaf(bT[4*r4+3],uu.w,t3);
      e0+=qq.x; e1+=qq.y; e2+=qq.z; e3+=qq.w;
      y0+=uu.x; y1+=uu.y; y2+=uu.z; y3+=uu.w;
    }
    float scol=(t0+t1)+(t2+t3)+b64*U64;
    float s64v=(e0+e1)+(e2+e3)+k6464*U64;             // dustbin col dot
    float su  =(y0+y1)+(y2+y3)+U64;                   // sum(U) for invalid cols
    V_l = cvalid ? (nu_l/scol) : (1.0f/su);
    V64 = nu64/s64v;
    __syncthreads();
  }
  uf[l]=logf(U_l); vf[l]=logf(V_l);
  if (l==0){ uf[64]=logf(U64); vf[64]=logf(V64); }
  __syncthreads();
  for (int e=l;e<65*65;e+=64){
    int r=e/65, c=e-65*r;
    Pg[e]=Ps[e]+uf[r]+vf[c]-nrm;
  }
}

// fine prep: s=exp(ms[:, :64, :64]); mutual top-3 + threshold + masks -> sm
__global__ __launch_bounds__(256) void fineprep_kernel(
    const float* __restrict__ P, const int* __restrict__ sel_t, const int* __restrict__ sel_s,
    float* __restrict__ smout){
  __shared__ float s[KK*KK];
  __shared__ unsigned long long rowm[KK], colm[KK];
  __shared__ int tmk[KK], smk[KK];
  int b=blockIdx.x, t=threadIdx.x;
  const float* Pb=P+(size_t)b*65*65;
  for (int e=t;e<KK*KK;e+=256){
    int r=e>>6, c=e&63;
    s[e]=expf(Pb[r*65+c]);
  }
  if (t<KK){ tmk[t]=(sel_t[b*KK+t]!=NPTS); smk[t]=(sel_s[b*KK+t]!=NPTS); }
  __syncthreads();
  if (t<KK){
    float v1=-1,v2=-1,v3=-1; int i1=0,i2=0,i3=0;
    const float* row=s+t*KK;
    for (int c=0;c<KK;c++){ float v=row[c];
      if (v>v1){v3=v2;i3=i2;v2=v1;i2=i1;v1=v;i1=c;}
      else if (v>v2){v3=v2;i3=i2;v2=v;i2=c;}
      else if (v>v3){v3=v;i3=c;}
    }
    rowm[t]=(1ULL<<i1)|(1ULL<<i2)|(1ULL<<i3);
  } else if (t<2*KK){
    int c=t-KK;
    float v1=-1,v2=-1,v3=-1; int i1=0,i2=0,i3=0;
    for (int r=0;r<KK;r++){ float v=s[r*KK+c];
      if (v>v1){v3=v2;i3=i2;v2=v1;i2=i1;v1=v;i1=r;}
      else if (v>v2){v3=v2;i3=i2;v2=v;i2=r;}
      else if (v>v3){v3=v;i3=r;}
    }
    colm[c]=(1ULL<<i1)|(1ULL<<i2)|(1ULL<<i3);
  }
  __syncthreads();
  for (int e=t;e<KK*KK;e+=256){
    int r=e>>6, c=e&63;
    float v=s[e];
    bool keep = ((rowm[r]>>c)&1ULL) && ((colm[c]>>r)&1ULL) && (v>0.05f) && tmk[r] && smk[c];
    smout[(size_t)b*KK*KK+e]= keep? v : 0.0f;
  }
}

extern "C" void kernel_launch(void* const* d_in, const int* in_sizes, int n_in,
                              void* d_out, int out_size, void* d_ws, size_t ws_size,
                              hipStream_t stream){
  const float* src_pts=(const float*)d_in[0];
  const float* tgt_pts=(const float*)d_in[1];
  const float* src_pf =(const float*)d_in[2];
  const float* tgt_pf =(const float*)d_in[3];
  const float* src_nf =(const float*)d_in[4];
  const float* tgt_nf =(const float*)d_in[5];
  const float* src_nx =(const float*)d_in[6];
  const float* tgt_nx =(const float*)d_in[7];
  const float* cw=(const float*)d_in[8];
  const float* cb=(const float*)d_in[9];
  const float* fw=(const float*)d_in[10];
  const float* fb=(const float*)d_in[11];
  const float* alpha=(const float*)d_in[12];

  char* ws=(char*)d_ws;
  size_t off=0;
  auto A=[&](size_t bytes)->char*{
    char* p=ws+off; off+=(bytes+255)&~(size_t)255; return p; };

  float* tf    =(float*)A((size_t)MN*DN*4);
  float* sfb   =(float*)A((size_t)MN*DN*4);
  float* tt    =(float*)A(MN*4);
  float* ssv   =(float*)A(MN*4);
  int*   p2n_s =(int*)A((size_t)NPTS*4);
  int*   p2n_t =(int*)A((size_t)NPTS*4);
  int*   cnt_s =(int*)A(MN*4);
  int*   cnt_t =(int*)A(MN*4);
  int*   list_s=(int*)A((size_t)MN*CAPL*4);
  int*   list_t=(int*)A((size_t)MN*CAPL*4);
  int*   knn_s =(int*)A((size_t)MN*KK*4);
  int*   knn_t =(int*)A((size_t)MN*KK*4);
  float* Smat  =(float*)A((size_t)MN*MN*4);
  unsigned* partial=(unsigned*)A((size_t)HBLK*256*4);
  unsigned* meta=(unsigned*)A(256);
  float* cand_v=(float*)A((size_t)CCAP*4);
  int*   cand_i=(int*)A((size_t)CCAP*4);
  int*   ci_t  =(int*)A(BCORR*4);
  int*   ci_s  =(int*)A(BCORR*4);
  int*   sel_t =(int*)A((size_t)BCORR*KK*4);
  int*   sel_s =(int*)A((size_t)BCORR*KK*4);
  float* feat_t=(float*)A((size_t)BCORR*KK*DN*4);
  float* feat_s=(float*)A((size_t)BCORR*KK*DN*4);
  float* smf   =(float*)A((size_t)BCORR*KK*KK*4);
  float* rs    =(float*)A(MN*4);
  float* csum  =(float*)A(MN*4);

  float* out=(float*)d_out;
  float* msout=out;
  float* tpout=out+(size_t)BCORR*65*65;
  float* spout=tpout+(size_t)OUTC*3;
  float* csout=spout+(size_t)OUTC*3;

  const int PB=(NPTS+255)/256;

  node_feat_kernel<<<MN,256,0,stream>>>(tgt_nf,cw,cb,tf,tt);
  node_feat_kernel<<<MN,256,0,stream>>>(src_nf,cw,cb,sfb,ssv);
  p2n_kernel<<<PB,256,0,stream>>>(src_pts,src_nx,p2n_s);
  p2n_kernel<<<PB,256,0,stream>>>(tgt_pts,tgt_nx,p2n_t);
  zero_u32_kernel<<<8,256,0,stream>>>((unsigned*)cnt_s,MN);
  zero_u32_kernel<<<8,256,0,stream>>>((unsigned*)cnt_t,MN);
  scatter_kernel<<<PB,256,0,stream>>>(p2n_s,cnt_s,list_s);
  scatter_kernel<<<PB,256,0,stream>>>(p2n_t,cnt_t,list_t);
  knn_kernel<<<MN,256,0,stream>>>(src_pts,src_nx,cnt_s,list_s,knn_s);
  knn_kernel<<<MN,256,0,stream>>>(tgt_pts,tgt_nx,cnt_t,list_t,knn_t);

  coarse_score_kernel<<<256,256,0,stream>>>(tf,sfb,tt,ssv,cnt_t,cnt_s,Smat);
  rowsum_kernel<<<MN,256,0,stream>>>(Smat,rs);
  colsum_kernel<<<MN,256,0,stream>>>(Smat,csum);
  dualnorm_kernel<<<4096,256,0,stream>>>(Smat,rs,csum);

  hist_coarse_kernel<<<HBLK,256,0,stream>>>(Smat,MN*MN,partial);
  scan_coarse_kernel<<<1,256,0,stream>>>(partial,HBLK,BCORR,meta);
  hist_fine_kernel<<<HBLK,256,0,stream>>>(Smat,MN*MN,meta,partial);
  scan_fine_kernel<<<1,256,0,stream>>>(partial,HBLK,BCORR,meta);
  compact_kernel<<<2048,256,0,stream>>>(Smat,MN*MN,meta,cand_v,cand_i,meta+1);
  zero_u32_kernel<<<1,256,0,stream>>>((unsigned*)ci_t,BCORR);
  zero_u32_kernel<<<1,256,0,stream>>>((unsigned*)ci_s,BCORR);
  rank_coarse_kernel<<<CCAP/256,256,0,stream>>>(cand_v,cand_i,meta,ci_t,ci_s);

  gather_sel_kernel<<<BCORR,KK,0,stream>>>(ci_t,knn_t,sel_t);
  gather_sel_kernel<<<BCORR,KK,0,stream>>>(ci_s,knn_s,sel_s);
  sel_feat_kernel<<<1024,256,0,stream>>>(sel_t,tgt_pf,fw,fb,feat_t);
  sel_feat_kernel<<<1024,256,0,stream>>>(sel_s,src_pf,fw,fb,feat_s);

  pbuild_kernel<<<BCORR,256,0,stream>>>(feat_t,feat_s,sel_t,sel_s,alpha,msout);
  ot_kernel<<<BCORR,64,0,stream>>>(msout,sel_t,sel_s);

  fineprep_kernel<<<BCORR,256,0,stream>>>(msout,sel_t,sel_s,smf);
  hist_coarse_kernel<<<HBLK,256,0,stream>>>(smf,BCORR*KK*KK,partial);
  scan_coarse_kernel<<<1,256,0,stream>>>(partial,HBLK,OUTC,meta);
  hist_fine_kernel<<<HBLK,256,0,stream>>>(smf,BCORR*KK*KK,meta,partial);
  scan_fine_kernel<<<1,256,0,stream>>>(partial,HBLK,OUTC,meta);
  compact_kernel<<<2048,256,0,stream>>>(smf,BCORR*KK*KK,meta,cand_v,cand_i,meta+1);
  zero_f32_kernel<<<28,256,0,stream>>>(tpout,OUTC*3*2+OUTC);
  rank_fine_kernel<<<CCAP/256,256,0,stream>>>(cand_v,cand_i,meta,sel_t,sel_s,
                                              tgt_pts,src_pts,tpout,spout,csout);
}